// Round 1
// baseline (1064.010 us; speedup 1.0000x reference)
//
#include <hip/hip_runtime.h>
#include <math.h>

constexpr int NB = 2;      // batch
constexpr int SL = 2048;   // sequence length
constexpr int NV = 1024;   // model dim
constexpr int NH = 16;     // heads
constexpr int DH = 64;     // head dim
constexpr float LN_EPS = 1e-3f;

// ---------------------------------------------------------------------------
// Projection GEMM: out[b,h,l,d] = sum_v A[b,l,v] * W[h,v,d]
// A: (NB*SL, NV) row-major. W: (NH, NV, DH). out: (NB*NH, SL, DH) row-major.
// Grid: (M/64, NH). Block 256 threads, 4x4 micro-tile.
__global__ __launch_bounds__(256)
void proj_kernel(const float* __restrict__ A, const float* __restrict__ W,
                 float* __restrict__ out) {
  __shared__ float Ast[16][68];  // [k][m] (transposed), pad to 68 (272B rows, 16B aligned)
  __shared__ float Ws[16][68];   // [k][n]
  const int t  = threadIdx.x;
  const int tx = t & 15;
  const int ty = t >> 4;
  const int m0 = blockIdx.x * 64;
  const int h  = blockIdx.y;

  const int lm = t >> 2;   // 0..63: A-tile row staged by this thread
  const int kq = t & 3;    // k-quad
  const int wk = t >> 4;   // 0..15: W-tile k row
  const int wn = t & 15;   // W-tile col quad

  const float* Arow  = A + (size_t)(m0 + lm) * NV;
  const float* Wbase = W + (size_t)h * NV * DH;

  float acc[4][4] = {};

  for (int k0 = 0; k0 < NV; k0 += 16) {
    __syncthreads();
    float4 av = *(const float4*)(Arow + k0 + kq * 4);
    Ast[kq*4+0][lm] = av.x;
    Ast[kq*4+1][lm] = av.y;
    Ast[kq*4+2][lm] = av.z;
    Ast[kq*4+3][lm] = av.w;
    *(float4*)&Ws[wk][wn*4] =
        *(const float4*)(Wbase + (size_t)(k0 + wk) * DH + wn*4);
    __syncthreads();
#pragma unroll
    for (int kk = 0; kk < 16; ++kk) {
      float4 a4 = *(const float4*)&Ast[kk][ty*4];
      float4 w4 = *(const float4*)&Ws[kk][tx*4];
      const float aa[4] = {a4.x, a4.y, a4.z, a4.w};
      const float ww[4] = {w4.x, w4.y, w4.z, w4.w};
#pragma unroll
      for (int i = 0; i < 4; ++i)
#pragma unroll
        for (int j = 0; j < 4; ++j)
          acc[i][j] += aa[i] * ww[j];
    }
  }

#pragma unroll
  for (int i = 0; i < 4; ++i) {
    const int r = m0 + ty*4 + i;       // global row = b*SL + l
    const int b = r >> 11;             // SL = 2048
    const int l = r & (SL - 1);
    float4 o4 = make_float4(acc[i][0], acc[i][1], acc[i][2], acc[i][3]);
    *(float4*)(out + ((size_t)(b*NH + h) * SL + l) * DH + tx*4) = o4;
  }
}

// ---------------------------------------------------------------------------
// Flash-style attention with FULL-ROW softmax denominator (reference applies
// masks AFTER softmax): l_sum accumulates exp over ALL m; PV accumulates only
// (m <= l) * vm[m]; epilogue multiplies qm[l] / l_sum.
// Grid: (SL/64, NB*NH). Block 256 threads. Q-tile 64 rows.
__global__ __launch_bounds__(256)
void attn_kernel(const float* __restrict__ Qg, const float* __restrict__ Kg,
                 const float* __restrict__ Vg, const int* __restrict__ qmask,
                 const int* __restrict__ vmask, float* __restrict__ Xout) {
  __shared__ float Qs [64][68];   // [i][d] row-major, scaled by 1/8
  __shared__ float Kst[64][68];   // [d][j] transposed
  __shared__ float Vs [64][68];   // [j][d] row-major
  __shared__ float Pt [64][68];   // [j][i] transposed P
  __shared__ float vmf[SL];       // value mask as float, whole row

  const int t  = threadIdx.x;
  const int tx = t & 15;          // col group (j or d = tx*4+..)
  const int ty = t >> 4;          // row group (i = ty*4+..)
  const int bh = blockIdx.y;
  const int b  = bh >> 4;         // NH = 16
  const int h  = bh & 15;
  const int l0 = blockIdx.x * 64;

  const float* Qb = Qg + (size_t)bh * SL * DH;
  const float* Kb = Kg + (size_t)bh * SL * DH;
  const float* Vb = Vg + (size_t)bh * SL * DH;

  // preload value mask (whole row) and Q tile (scaled)
  for (int j = t; j < SL; j += 256) vmf[j] = (float)vmask[b * SL + j];
#pragma unroll
  for (int p = 0; p < 4; ++p) {
    int idx = p * 256 + t;
    int i = idx >> 4, dq = idx & 15;
    float4 q4 = *(const float4*)(Qb + (size_t)(l0 + i) * DH + dq*4);
    q4.x *= 0.125f; q4.y *= 0.125f; q4.z *= 0.125f; q4.w *= 0.125f;
    *(float4*)&Qs[i][dq*4] = q4;
  }

  float O[4][4] = {};
  float m_run[4] = {-1e30f, -1e30f, -1e30f, -1e30f};
  float l_run[4] = {};

  for (int mt = 0; mt < SL / 64; ++mt) {
    const int m0 = mt * 64;
    __syncthreads();   // prev PV done with Kst/Vs/Pt
    // stage K (transposed) and V
#pragma unroll
    for (int p = 0; p < 4; ++p) {
      int idx = p * 256 + t;
      int j = idx >> 4, dq = idx & 15;
      float4 k4 = *(const float4*)(Kb + (size_t)(m0 + j) * DH + dq*4);
      Kst[dq*4+0][j] = k4.x;
      Kst[dq*4+1][j] = k4.y;
      Kst[dq*4+2][j] = k4.z;
      Kst[dq*4+3][j] = k4.w;
      *(float4*)&Vs[j][dq*4] =
          *(const float4*)(Vb + (size_t)(m0 + j) * DH + dq*4);
    }
    __syncthreads();

    // S[i][j] = Q[i][:] . K[j][:]  (i = ty*4+ii, j = tx*4+jj)
    float S[4][4] = {};
#pragma unroll
    for (int dq = 0; dq < 16; ++dq) {
      float qa[4][4], kb4[4][4];
#pragma unroll
      for (int ii = 0; ii < 4; ++ii)
        *(float4*)qa[ii] = *(const float4*)&Qs[ty*4+ii][dq*4];
#pragma unroll
      for (int dd = 0; dd < 4; ++dd)
        *(float4*)kb4[dd] = *(const float4*)&Kst[dq*4+dd][tx*4];
#pragma unroll
      for (int ii = 0; ii < 4; ++ii)
#pragma unroll
        for (int dd = 0; dd < 4; ++dd)
#pragma unroll
          for (int jj = 0; jj < 4; ++jj)
            S[ii][jj] += qa[ii][dd] * kb4[dd][jj];
    }

    // online softmax update; row r = ty*4+ii owned by the 16 lanes of group ty
    float e[4][4];
    float alpha[4];
#pragma unroll
    for (int ii = 0; ii < 4; ++ii) {
      float mx = fmaxf(fmaxf(S[ii][0], S[ii][1]), fmaxf(S[ii][2], S[ii][3]));
#pragma unroll
      for (int off = 1; off < 16; off <<= 1)
        mx = fmaxf(mx, __shfl_xor(mx, off));
      float m_new = fmaxf(m_run[ii], mx);
      alpha[ii] = __expf(m_run[ii] - m_new);
      float ps = 0.f;
#pragma unroll
      for (int jj = 0; jj < 4; ++jj) {
        float ee = __expf(S[ii][jj] - m_new);
        e[ii][jj] = ee;
        ps += ee;              // denominator over ALL m (unmasked)
      }
#pragma unroll
      for (int off = 1; off < 16; off <<= 1)
        ps += __shfl_xor(ps, off);
      l_run[ii] = l_run[ii] * alpha[ii] + ps;
      m_run[ii] = m_new;
    }

    // masked P -> Pt[j][i]; rescale O
#pragma unroll
    for (int ii = 0; ii < 4; ++ii) {
      const int lg = l0 + ty*4 + ii;
#pragma unroll
      for (int jj = 0; jj < 4; ++jj) {
        const int mg = m0 + tx*4 + jj;
        float p = (mg <= lg) ? e[ii][jj] * vmf[mg] : 0.f;
        Pt[tx*4+jj][ty*4+ii] = p;
      }
#pragma unroll
      for (int dd = 0; dd < 4; ++dd) O[ii][dd] *= alpha[ii];
    }
    __syncthreads();   // Pt ready

    // O[i][d] += sum_j P[i][j] * V[j][d]
#pragma unroll
    for (int jq = 0; jq < 16; ++jq) {
      float pv[4][4], vv[4][4];
#pragma unroll
      for (int jj = 0; jj < 4; ++jj) {
        *(float4*)pv[jj] = *(const float4*)&Pt[jq*4+jj][ty*4];
        *(float4*)vv[jj] = *(const float4*)&Vs[jq*4+jj][tx*4];
      }
#pragma unroll
      for (int jj = 0; jj < 4; ++jj)
#pragma unroll
        for (int ii = 0; ii < 4; ++ii)
#pragma unroll
          for (int dd = 0; dd < 4; ++dd)
            O[ii][dd] += pv[jj][ii] * vv[jj][dd];
    }
  }

  // epilogue: heads[b,l,h,d] = O * qm[l] / l_sum
#pragma unroll
  for (int ii = 0; ii < 4; ++ii) {
    const int lg = l0 + ty*4 + ii;
    const float qmv = (float)qmask[b * SL + lg];
    const float inv = qmv / l_run[ii];
    float4 o4 = make_float4(O[ii][0]*inv, O[ii][1]*inv, O[ii][2]*inv, O[ii][3]*inv);
    *(float4*)(Xout + ((size_t)(b * SL + lg) * NH + h) * DH + tx*4) = o4;
  }
}

// ---------------------------------------------------------------------------
// Residual + LayerNorm over last dim (V=1024). One block per row, 256 threads.
__global__ __launch_bounds__(256)
void ln_kernel(const float* __restrict__ X, const float* __restrict__ query,
               const float* __restrict__ gamma, const float* __restrict__ beta,
               float* __restrict__ out) {
  const int row = blockIdx.x;
  const int t = threadIdx.x;
  const float* xr = X + (size_t)row * NV;
  const float* qr = query + (size_t)row * NV;
  float4 xv = *(const float4*)(xr + t*4);
  float4 qv = *(const float4*)(qr + t*4);
  float y[4] = {xv.x+qv.x, xv.y+qv.y, xv.z+qv.z, xv.w+qv.w};
  float s  = y[0] + y[1] + y[2] + y[3];
  float ss = y[0]*y[0] + y[1]*y[1] + y[2]*y[2] + y[3]*y[3];
#pragma unroll
  for (int off = 1; off < 64; off <<= 1) {
    s  += __shfl_xor(s, off);
    ss += __shfl_xor(ss, off);
  }
  __shared__ float ws_s[4], ws_ss[4];
  const int wid = t >> 6;
  if ((t & 63) == 0) { ws_s[wid] = s; ws_ss[wid] = ss; }
  __syncthreads();
  s  = ws_s[0] + ws_s[1] + ws_s[2] + ws_s[3];
  ss = ws_ss[0] + ws_ss[1] + ws_ss[2] + ws_ss[3];
  const float mu   = s * (1.f / NV);
  const float var  = ss * (1.f / NV) - mu * mu;
  const float rstd = rsqrtf(var + LN_EPS);
  float4 gv = *(const float4*)(gamma + t*4);
  float4 bv = *(const float4*)(beta + t*4);
  float4 o;
  o.x = gv.x * (y[0] - mu) * rstd + bv.x;
  o.y = gv.y * (y[1] - mu) * rstd + bv.y;
  o.z = gv.z * (y[2] - mu) * rstd + bv.z;
  o.w = gv.w * (y[3] - mu) * rstd + bv.w;
  *(float4*)(out + (size_t)row * NV + t*4) = o;
}

// ---------------------------------------------------------------------------
extern "C" void kernel_launch(void* const* d_in, const int* in_sizes, int n_in,
                              void* d_out, int out_size, void* d_ws, size_t ws_size,
                              hipStream_t stream) {
  const float* query = (const float*)d_in[0];
  const float* key_t = (const float*)d_in[1];
  const float* value = (const float*)d_in[2];
  const float* Wq    = (const float*)d_in[3];
  const float* Wk    = (const float*)d_in[4];
  const float* Wv    = (const float*)d_in[5];
  const float* gamma = (const float*)d_in[6];
  const float* beta  = (const float*)d_in[7];
  const int*   qmask = (const int*)d_in[8];
  const int*   vmask = (const int*)d_in[9];
  float* out = (float*)d_out;

  const size_t per = (size_t)NB * NH * SL * DH;  // 4,194,304 floats
  float* Qws = (float*)d_ws;
  float* Kws = Qws + per;
  float* Vws = Kws + per;
  // heads-concat scratch X lives in d_out; ln_kernel rewrites it in place.

  dim3 gp(NB * SL / 64, NH);
  proj_kernel<<<gp, 256, 0, stream>>>(query, Wq, Qws);
  proj_kernel<<<gp, 256, 0, stream>>>(key_t, Wk, Kws);
  proj_kernel<<<gp, 256, 0, stream>>>(value, Wv, Vws);

  dim3 ga(SL / 64, NB * NH);
  attn_kernel<<<ga, 256, 0, stream>>>(Qws, Kws, Vws, qmask, vmask, out);

  ln_kernel<<<NB * SL, 256, 0, stream>>>(out, query, gamma, beta, out);
}

// Round 2
// 419.407 us; speedup vs baseline: 2.5369x; 2.5369x over previous
//
#include <hip/hip_runtime.h>
#include <math.h>

constexpr int NB = 2;      // batch
constexpr int SL = 2048;   // sequence length
constexpr int NV = 1024;   // model dim
constexpr int NH = 16;     // heads
constexpr int DH = 64;     // head dim
constexpr float LN_EPS = 1e-3f;

typedef __bf16 bf16_t;
typedef __bf16 v8bf __attribute__((ext_vector_type(8)));
typedef float  v4f  __attribute__((ext_vector_type(4)));

// ---------------------------------------------------------------------------
// DPP 16-lane reductions (VALU pipe; rows of 16 lanes match the MFMA C-layout
// reduction groups: col = lane&15, 16 consecutive lanes per row-group).
template <int CTRL>
__device__ __forceinline__ float dpp_mov(float x) {
  int xi = __builtin_bit_cast(int, x);
  int r  = __builtin_amdgcn_update_dpp(xi, xi, CTRL, 0xF, 0xF, false);
  return __builtin_bit_cast(float, r);
}
__device__ __forceinline__ float red_max16(float x) {
  x = fmaxf(x, dpp_mov<0x121>(x));  // row_ror:1
  x = fmaxf(x, dpp_mov<0x122>(x));  // row_ror:2
  x = fmaxf(x, dpp_mov<0x124>(x));  // row_ror:4
  x = fmaxf(x, dpp_mov<0x128>(x));  // row_ror:8
  return x;
}
__device__ __forceinline__ float red_sum16(float x) {
  x += dpp_mov<0x121>(x);
  x += dpp_mov<0x122>(x);
  x += dpp_mov<0x124>(x);
  x += dpp_mov<0x128>(x);
  return x;
}

__device__ __forceinline__ v8bf cvt8(float4 a, float4 b) {
  v8bf v;
  v[0] = (bf16_t)a.x; v[1] = (bf16_t)a.y; v[2] = (bf16_t)a.z; v[3] = (bf16_t)a.w;
  v[4] = (bf16_t)b.x; v[5] = (bf16_t)b.y; v[6] = (bf16_t)b.z; v[7] = (bf16_t)b.w;
  return v;
}
__device__ __forceinline__ unsigned pack_bf16(float a, float b) {
  unsigned short ua = __builtin_bit_cast(unsigned short, (bf16_t)a);
  unsigned short ub = __builtin_bit_cast(unsigned short, (bf16_t)b);
  return (unsigned)ua | ((unsigned)ub << 16);
}

// ---------------------------------------------------------------------------
// Projection: out[b,h,l,d] = scale * sum_v A[b*SL+l, v] * W[h, v, d]
// Treated as one GEMM: M=4096, N=1024 (n = h*64+d), K=1024. bf16 MFMA.
// Block: 128x128 tile, 256 threads (4 waves in 2x2), BK=64.
__global__ __launch_bounds__(256)
void proj_mfma(const float* __restrict__ A, const float* __restrict__ Wg,
               bf16_t* __restrict__ out, float scale) {
  __shared__ bf16_t As[128][72];  // A[m][k], pitch 72 (144B rows, 16B aligned)
  __shared__ bf16_t Wt[128][72];  // Wcat^T: [n][k]

  const int t    = threadIdx.x;
  const int w    = t >> 6;
  const int lane = t & 63;
  const int g    = lane >> 4;    // quad group
  const int lx   = lane & 15;
  const int m0   = blockIdx.x * 128;
  const int n0   = blockIdx.y * 128;
  const int rbase = (w >> 1) * 64;  // wave row offset in tile
  const int cbase = (w & 1) * 64;   // wave col offset in tile

  // A staging assignment: 2 threads per row, 32 floats each
  const int arow  = t >> 1;
  const int ahalf = (t & 1) * 32;
  const float* Abase = A + (size_t)(m0 + arow) * NV + ahalf;

  // W staging assignment: thread covers n-quad (4 n) x k-pairs
  const int nq  = t & 31;         // n-quad: n = 4*nq .. 4*nq+3
  const int kp  = t >> 5;         // k-pair base: k = 2*kp (+16*it)
  const int nn  = 4 * nq;
  const int wh  = (n0 + nn) >> 6;
  const int wd  = (n0 + nn) & 63;
  const float* Wbase = Wg + (size_t)wh * (NV * DH) + wd;

  v4f acc[4][4] = {};  // [rt][ct]

  for (int k0 = 0; k0 < NV; k0 += 64) {
    __syncthreads();
    // stage A (fp32 -> bf16)
    {
      const float* src = Abase + k0;
#pragma unroll
      for (int s = 0; s < 4; ++s) {
        float4 f0 = *(const float4*)(src + s * 8);
        float4 f1 = *(const float4*)(src + s * 8 + 4);
        *(v8bf*)&As[arow][ahalf + s * 8] = cvt8(f0, f1);
      }
    }
    // stage W transposed (fp32 -> bf16), k-pairs packed as b32
#pragma unroll
    for (int it = 0; it < 4; ++it) {
      int kk = 2 * kp + 16 * it;
      float4 r0 = *(const float4*)(Wbase + (size_t)(k0 + kk) * DH);
      float4 r1 = *(const float4*)(Wbase + (size_t)(k0 + kk + 1) * DH);
      *(unsigned*)&Wt[nn + 0][kk] = pack_bf16(r0.x, r1.x);
      *(unsigned*)&Wt[nn + 1][kk] = pack_bf16(r0.y, r1.y);
      *(unsigned*)&Wt[nn + 2][kk] = pack_bf16(r0.z, r1.z);
      *(unsigned*)&Wt[nn + 3][kk] = pack_bf16(r0.w, r1.w);
    }
    __syncthreads();
    // compute: 2 k-steps of 32
#pragma unroll
    for (int ks = 0; ks < 2; ++ks) {
      v8bf af[4], bf[4];
#pragma unroll
      for (int rt = 0; rt < 4; ++rt)
        af[rt] = *(const v8bf*)&As[rbase + rt * 16 + lx][ks * 32 + g * 8];
#pragma unroll
      for (int ct = 0; ct < 4; ++ct)
        bf[ct] = *(const v8bf*)&Wt[cbase + ct * 16 + lx][ks * 32 + g * 8];
#pragma unroll
      for (int rt = 0; rt < 4; ++rt)
#pragma unroll
        for (int ct = 0; ct < 4; ++ct)
          acc[rt][ct] = __builtin_amdgcn_mfma_f32_16x16x32_bf16(
              af[rt], bf[ct], acc[rt][ct], 0, 0, 0);
    }
  }

  // store bf16, scaled. C-layout: row=(lane>>4)*4+reg, col=lane&15.
#pragma unroll
  for (int rt = 0; rt < 4; ++rt) {
#pragma unroll
    for (int reg = 0; reg < 4; ++reg) {
      const int row = m0 + rbase + rt * 16 + g * 4 + reg;
      const int b = row >> 11;
      const int l = row & (SL - 1);
#pragma unroll
      for (int ct = 0; ct < 4; ++ct) {
        const int n = n0 + cbase + ct * 16 + lx;
        const int h = n >> 6, d = n & 63;
        out[((size_t)(b * NH + h) * SL + l) * DH + d] =
            (bf16_t)(acc[rt][ct][reg] * scale);
      }
    }
  }
}

// ---------------------------------------------------------------------------
// Fused attention, bf16 MFMA. Full-row softmax denominator (reference masks
// AFTER softmax): l_run sums exp over ALL m; PV only accumulates
// (m <= l) * vm[m]; epilogue applies qm[l] / l_run.
// Block: 128 q-rows (4 waves x 32), m-tiles of 64. Grid (SL/128, NB*NH).
__global__ __launch_bounds__(256)
void attn_mfma(const bf16_t* __restrict__ Qg, const bf16_t* __restrict__ Kg,
               const bf16_t* __restrict__ Vg, const int* __restrict__ qmask,
               const int* __restrict__ vmask, float* __restrict__ Xout) {
  __shared__ bf16_t Qs[128][72];    // Q[i][d]  (pre-scaled by 1/8 in proj)
  __shared__ bf16_t Ks[64][72];     // K[j][d]  (row-major == B-operand K^T)
  __shared__ bf16_t Vt[64][72];     // V^T[d][m]
  __shared__ bf16_t Ps[4][32][72];  // per-wave P strip [r][m]
  __shared__ float  vmf[SL];

  const int t    = threadIdx.x;
  const int w    = t >> 6;
  const int lane = t & 63;
  const int g    = lane >> 4;
  const int lx   = lane & 15;
  const int bh   = blockIdx.y;
  const int b    = bh >> 4;
  const int h    = bh & 15;
  const int qb   = blockIdx.x;
  const int l0   = qb * 128;

  const bf16_t* Qb = Qg + (size_t)bh * SL * DH;
  const bf16_t* Kb = Kg + (size_t)bh * SL * DH;
  const bf16_t* Vb = Vg + (size_t)bh * SL * DH;

  for (int j = t; j < SL; j += 256) vmf[j] = (float)vmask[b * SL + j];
#pragma unroll
  for (int s = 0; s < 4; ++s) {  // stage Q tile (128 x 64 bf16)
    int idx = s * 256 + t;
    int row = idx >> 3, dseg = idx & 7;
    *(uint4*)&Qs[row][dseg * 8] =
        *(const uint4*)&Qb[(size_t)(l0 + row) * DH + dseg * 8];
  }

  v4f O[2][4] = {};           // [rt][dt]
  float m_run[2][4], l_run[2][4];
#pragma unroll
  for (int rt = 0; rt < 2; ++rt)
#pragma unroll
    for (int r = 0; r < 4; ++r) { m_run[rt][r] = -1e30f; l_run[rt][r] = 0.f; }

  const int vtp = t & 31;   // V-transpose: m-pair index
  const int vtd = t >> 5;   // d-octet

  for (int mt = 0; mt < SL / 64; ++mt) {
    const int m0 = mt * 64;
    const bool active = (m0 <= l0 + 127);
    __syncthreads();  // all waves done with prev Ks/Vt
    // stage K (row-major)
#pragma unroll
    for (int s = 0; s < 2; ++s) {
      int idx = s * 256 + t;
      int row = idx >> 3, dseg = idx & 7;
      *(uint4*)&Ks[row][dseg * 8] =
          *(const uint4*)&Kb[(size_t)(m0 + row) * DH + dseg * 8];
    }
    if (active) {  // stage V transposed: Vt[d][m], packed m-pairs
      const bf16_t* v0 = Vb + (size_t)(m0 + 2 * vtp) * DH + vtd * 8;
      uint4 r0 = *(const uint4*)v0;
      uint4 r1 = *(const uint4*)(v0 + DH);
      const unsigned w0[4] = {r0.x, r0.y, r0.z, r0.w};
      const unsigned w1[4] = {r1.x, r1.y, r1.z, r1.w};
#pragma unroll
      for (int i = 0; i < 4; ++i) {
        unsigned lo = (w0[i] & 0xffffu) | (w1[i] << 16);
        unsigned hi = (w0[i] >> 16) | (w1[i] & 0xffff0000u);
        *(unsigned*)&Vt[vtd * 8 + 2 * i][2 * vtp]     = lo;
        *(unsigned*)&Vt[vtd * 8 + 2 * i + 1][2 * vtp] = hi;
      }
    }
    __syncthreads();

    // S = Q . K^T  (wave strip: 32 rows x 64 cols)
    v4f S[2][4] = {};
#pragma unroll
    for (int ks = 0; ks < 2; ++ks) {
      v8bf qf[2], kf[4];
#pragma unroll
      for (int rt = 0; rt < 2; ++rt)
        qf[rt] = *(const v8bf*)&Qs[w * 32 + rt * 16 + lx][ks * 32 + g * 8];
#pragma unroll
      for (int ct = 0; ct < 4; ++ct)
        kf[ct] = *(const v8bf*)&Ks[ct * 16 + lx][ks * 32 + g * 8];
#pragma unroll
      for (int rt = 0; rt < 2; ++rt)
#pragma unroll
        for (int ct = 0; ct < 4; ++ct)
          S[rt][ct] = __builtin_amdgcn_mfma_f32_16x16x32_bf16(
              qf[rt], kf[ct], S[rt][ct], 0, 0, 0);
    }

    // online softmax (rows g*4+reg per lane-group; reduce over 16 lanes)
#pragma unroll
    for (int rt = 0; rt < 2; ++rt) {
#pragma unroll
      for (int reg = 0; reg < 4; ++reg) {
        float s0 = S[rt][0][reg], s1 = S[rt][1][reg];
        float s2 = S[rt][2][reg], s3 = S[rt][3][reg];
        float mx = fmaxf(fmaxf(s0, s1), fmaxf(s2, s3));
        mx = red_max16(mx);
        float mold = m_run[rt][reg];
        float mnew = fmaxf(mold, mx);
        float al = __expf(mold - mnew);
        float e0 = __expf(s0 - mnew), e1 = __expf(s1 - mnew);
        float e2 = __expf(s2 - mnew), e3 = __expf(s3 - mnew);
        float ps = red_sum16(e0 + e1 + e2 + e3);
        l_run[rt][reg] = l_run[rt][reg] * al + ps;
        m_run[rt][reg] = mnew;
#pragma unroll
        for (int dt = 0; dt < 4; ++dt) O[rt][dt][reg] *= al;
        if (active) {
          const int lg = l0 + w * 32 + rt * 16 + g * 4 + reg;
          const int rloc = rt * 16 + g * 4 + reg;
          {
            int mg = m0 + 0 * 16 + lx;
            Ps[w][rloc][0 * 16 + lx] = (bf16_t)((mg <= lg) ? e0 * vmf[mg] : 0.f);
            mg = m0 + 1 * 16 + lx;
            Ps[w][rloc][1 * 16 + lx] = (bf16_t)((mg <= lg) ? e1 * vmf[mg] : 0.f);
            mg = m0 + 2 * 16 + lx;
            Ps[w][rloc][2 * 16 + lx] = (bf16_t)((mg <= lg) ? e2 * vmf[mg] : 0.f);
            mg = m0 + 3 * 16 + lx;
            Ps[w][rloc][3 * 16 + lx] = (bf16_t)((mg <= lg) ? e3 * vmf[mg] : 0.f);
          }
        }
      }
    }

    if (active) {  // O += P . V   (wave-private Ps, no block barrier needed)
#pragma unroll
      for (int ks = 0; ks < 2; ++ks) {
        v8bf pf[2], vf[4];
#pragma unroll
        for (int rt = 0; rt < 2; ++rt)
          pf[rt] = *(const v8bf*)&Ps[w][rt * 16 + lx][ks * 32 + g * 8];
#pragma unroll
        for (int dt = 0; dt < 4; ++dt)
          vf[dt] = *(const v8bf*)&Vt[dt * 16 + lx][ks * 32 + g * 8];
#pragma unroll
        for (int rt = 0; rt < 2; ++rt)
#pragma unroll
          for (int dt = 0; dt < 4; ++dt)
            O[rt][dt] = __builtin_amdgcn_mfma_f32_16x16x32_bf16(
                pf[rt], vf[dt], O[rt][dt], 0, 0, 0);
      }
    }
  }

  // epilogue: X[b,l,h*64+d] = O * qm[l] / l_run
#pragma unroll
  for (int rt = 0; rt < 2; ++rt) {
#pragma unroll
    for (int reg = 0; reg < 4; ++reg) {
      const int lg = l0 + w * 32 + rt * 16 + g * 4 + reg;
      const float inv = (float)qmask[b * SL + lg] / l_run[rt][reg];
#pragma unroll
      for (int dt = 0; dt < 4; ++dt)
        Xout[((size_t)(b * SL + lg) * NH + h) * DH + dt * 16 + lx] =
            O[rt][dt][reg] * inv;
    }
  }
}

// ---------------------------------------------------------------------------
// Residual + LayerNorm over last dim (V=1024). One block per row, 256 threads.
__global__ __launch_bounds__(256)
void ln_kernel(const float* __restrict__ X, const float* __restrict__ query,
               const float* __restrict__ gamma, const float* __restrict__ beta,
               float* __restrict__ out) {
  const int row = blockIdx.x;
  const int t = threadIdx.x;
  const float* xr = X + (size_t)row * NV;
  const float* qr = query + (size_t)row * NV;
  float4 xv = *(const float4*)(xr + t * 4);
  float4 qv = *(const float4*)(qr + t * 4);
  float y[4] = {xv.x + qv.x, xv.y + qv.y, xv.z + qv.z, xv.w + qv.w};
  float s  = y[0] + y[1] + y[2] + y[3];
  float ss = y[0]*y[0] + y[1]*y[1] + y[2]*y[2] + y[3]*y[3];
#pragma unroll
  for (int off = 1; off < 64; off <<= 1) {
    s  += __shfl_xor(s, off);
    ss += __shfl_xor(ss, off);
  }
  __shared__ float ws_s[4], ws_ss[4];
  const int wid = t >> 6;
  if ((t & 63) == 0) { ws_s[wid] = s; ws_ss[wid] = ss; }
  __syncthreads();
  s  = ws_s[0] + ws_s[1] + ws_s[2] + ws_s[3];
  ss = ws_ss[0] + ws_ss[1] + ws_ss[2] + ws_ss[3];
  const float mu   = s * (1.f / NV);
  const float var  = ss * (1.f / NV) - mu * mu;
  const float rstd = rsqrtf(var + LN_EPS);
  float4 gv = *(const float4*)(gamma + t * 4);
  float4 bv = *(const float4*)(beta + t * 4);
  float4 o;
  o.x = gv.x * (y[0] - mu) * rstd + bv.x;
  o.y = gv.y * (y[1] - mu) * rstd + bv.y;
  o.z = gv.z * (y[2] - mu) * rstd + bv.z;
  o.w = gv.w * (y[3] - mu) * rstd + bv.w;
  *(float4*)(out + (size_t)row * NV + t * 4) = o;
}

// ---------------------------------------------------------------------------
extern "C" void kernel_launch(void* const* d_in, const int* in_sizes, int n_in,
                              void* d_out, int out_size, void* d_ws, size_t ws_size,
                              hipStream_t stream) {
  const float* query = (const float*)d_in[0];
  const float* key_t = (const float*)d_in[1];
  const float* value = (const float*)d_in[2];
  const float* Wq    = (const float*)d_in[3];
  const float* Wk    = (const float*)d_in[4];
  const float* Wv    = (const float*)d_in[5];
  const float* gamma = (const float*)d_in[6];
  const float* beta  = (const float*)d_in[7];
  const int*   qmask = (const int*)d_in[8];
  const int*   vmask = (const int*)d_in[9];
  float* out = (float*)d_out;

  const size_t per = (size_t)NB * NH * SL * DH;  // 4,194,304 elements
  bf16_t* Qws = (bf16_t*)d_ws;
  bf16_t* Kws = Qws + per;
  bf16_t* Vws = Kws + per;

  dim3 gp(NB * SL / 128, NV / 128);
  proj_mfma<<<gp, 256, 0, stream>>>(query, Wq, Qws, 0.125f);  // Q pre-scaled
  proj_mfma<<<gp, 256, 0, stream>>>(key_t, Wk, Kws, 1.0f);
  proj_mfma<<<gp, 256, 0, stream>>>(value, Wv, Vws, 1.0f);

  dim3 ga(SL / 128, NB * NH);
  attn_mfma<<<ga, 256, 0, stream>>>(Qws, Kws, Vws, qmask, vmask, out);

  ln_kernel<<<NB * SL, 256, 0, stream>>>(out, query, gamma, beta, out);
}

// Round 3
// 406.391 us; speedup vs baseline: 2.6182x; 1.0320x over previous
//
#include <hip/hip_runtime.h>
#include <math.h>

constexpr int NB = 2;      // batch
constexpr int SL = 2048;   // sequence length
constexpr int NV = 1024;   // model dim
constexpr int NH = 16;     // heads
constexpr int DH = 64;     // head dim
constexpr float LN_EPS = 1e-3f;

typedef __bf16 bf16_t;
typedef __bf16 v8bf __attribute__((ext_vector_type(8)));
typedef float  v4f  __attribute__((ext_vector_type(4)));

__device__ __forceinline__ v8bf cvt8(float4 a, float4 b) {
  v8bf v;
  v[0] = (bf16_t)a.x; v[1] = (bf16_t)a.y; v[2] = (bf16_t)a.z; v[3] = (bf16_t)a.w;
  v[4] = (bf16_t)b.x; v[5] = (bf16_t)b.y; v[6] = (bf16_t)b.z; v[7] = (bf16_t)b.w;
  return v;
}
__device__ __forceinline__ unsigned pack_bf16(float a, float b) {
  unsigned short ua = __builtin_bit_cast(unsigned short, (bf16_t)a);
  unsigned short ub = __builtin_bit_cast(unsigned short, (bf16_t)b);
  return (unsigned)ua | ((unsigned)ub << 16);
}

// ---------------------------------------------------------------------------
// W transpose+convert: W[h][v][d] fp32 -> Wt[z][n=h*64+d][v] bf16 (B-frag
// friendly: k=v contiguous). Scale (1/8 * log2e) folded into Wq.
__global__ __launch_bounds__(256)
void wcvt(const float* __restrict__ Wq, const float* __restrict__ Wk,
          const float* __restrict__ Wv, bf16_t* __restrict__ Wt) {
  __shared__ float ls[64][65];
  const int z = blockIdx.z;
  const float* W = z == 0 ? Wq : (z == 1 ? Wk : Wv);
  const float sc = z == 0 ? 0.125f * 1.44269504f : 1.0f;
  const int h = blockIdx.y, v0 = blockIdx.x * 64;
  const int t = threadIdx.x;
  const int rr = t >> 4, c4 = t & 15;
  const float* src = W + ((size_t)h * NV + v0) * DH;
#pragma unroll
  for (int it = 0; it < 4; ++it) {
    float4 f = *(const float4*)(src + (size_t)(rr + it * 16) * DH + c4 * 4);
    ls[rr + it * 16][c4 * 4 + 0] = f.x;
    ls[rr + it * 16][c4 * 4 + 1] = f.y;
    ls[rr + it * 16][c4 * 4 + 2] = f.z;
    ls[rr + it * 16][c4 * 4 + 3] = f.w;
  }
  __syncthreads();
  const int dd = t >> 2, vq = t & 3;
  bf16_t tmp[16];
#pragma unroll
  for (int i = 0; i < 16; ++i) tmp[i] = (bf16_t)(ls[vq * 16 + i][dd] * sc);
  bf16_t* dst = Wt + ((size_t)z * NV + h * 64 + dd) * NV + v0 + vq * 16;
  *(v8bf*)dst = *(v8bf*)&tmp[0];
  *(v8bf*)(dst + 8) = *(v8bf*)&tmp[8];
}

// ---------------------------------------------------------------------------
// Projection GEMM, no LDS, no barriers. out[b,h,l,d] = A(M=4096,K=1024) x
// Wt^T(N=1024). A-frags converted fp32->bf16 in-register; W-frags direct bf16.
// Grid (32, 8, 3); 256 threads = 4 waves in 2x2; each wave 64x64.
__global__ __launch_bounds__(256, 3)
void proj_mfma(const float* __restrict__ A0, const float* __restrict__ A1,
               const float* __restrict__ A2, const bf16_t* __restrict__ Wtb,
               bf16_t* __restrict__ O0, bf16_t* __restrict__ O1,
               bf16_t* __restrict__ O2) {
  const int z = blockIdx.z;
  const float*  A   = z == 0 ? A0 : (z == 1 ? A1 : A2);
  bf16_t*       out = z == 0 ? O0 : (z == 1 ? O1 : O2);
  const bf16_t* W   = Wtb + (size_t)z * NV * NV;

  const int t = threadIdx.x, w = t >> 6, lane = t & 63;
  const int g = lane >> 4, lx = lane & 15;
  const int m0 = blockIdx.x * 128 + (w >> 1) * 64;
  const int n0 = blockIdx.y * 128 + (w & 1) * 64;

  v4f acc[4][4] = {};
  const float*  Arow = A + (size_t)(m0 + lx) * NV + g * 8;
  const bf16_t* Wrow = W + (size_t)(n0 + lx) * NV + g * 8;

#pragma unroll 2
  for (int k0 = 0; k0 < NV; k0 += 32) {
    v8bf af[4], wf[4];
#pragma unroll
    for (int rt = 0; rt < 4; ++rt) {
      const float* p = Arow + (size_t)rt * 16 * NV + k0;
      float4 f0 = *(const float4*)p;
      float4 f1 = *(const float4*)(p + 4);
      af[rt] = cvt8(f0, f1);
    }
#pragma unroll
    for (int ct = 0; ct < 4; ++ct)
      wf[ct] = *(const v8bf*)(Wrow + (size_t)ct * 16 * NV + k0);
#pragma unroll
    for (int rt = 0; rt < 4; ++rt)
#pragma unroll
      for (int ct = 0; ct < 4; ++ct)
        acc[rt][ct] = __builtin_amdgcn_mfma_f32_16x16x32_bf16(
            af[rt], wf[ct], acc[rt][ct], 0, 0, 0);
  }

#pragma unroll
  for (int rt = 0; rt < 4; ++rt) {
#pragma unroll
    for (int reg = 0; reg < 4; ++reg) {
      const int row = m0 + rt * 16 + g * 4 + reg;
      const int b = row >> 11, l = row & (SL - 1);
#pragma unroll
      for (int ct = 0; ct < 4; ++ct) {
        const int n = n0 + ct * 16 + lx;
        const int h = n >> 6, d = n & 63;
        out[((size_t)(b * NH + h) * SL + l) * DH + d] = (bf16_t)acc[rt][ct][reg];
      }
    }
  }
}

// ---------------------------------------------------------------------------
// Fused attention. Reference semantics: softmax over ALL m (denominator
// unmasked), then post-softmax masking (tril, vm) on the numerator, qm at the
// epilogue. No max-tracking (scores ~N(0,1), exp2 safe; log2e folded into Q).
// S^T = K.Q^T via MFMA so masked P packs into b64 LDS writes.
// Block: 64 q-rows, 4 waves x 16 rows. Grid (SL/64, NB*NH).
__global__ __launch_bounds__(256, 4)
void attn_mfma(const bf16_t* __restrict__ Qg, const bf16_t* __restrict__ Kg,
               const bf16_t* __restrict__ Vg, const int* __restrict__ qmask,
               const int* __restrict__ vmask, float* __restrict__ Xout) {
  __shared__ bf16_t Vt[64][72];     // V^T[d][m], vm-masked
  __shared__ bf16_t Ps[4][16][72];  // per-wave P strip [l][m]

  const int t = threadIdx.x, w = t >> 6, lane = t & 63;
  const int g = lane >> 4, lx = lane & 15;
  const int bh = blockIdx.y, b = bh >> 4, h = bh & 15;
  const int qb = blockIdx.x, l0 = qb * 64;

  const bf16_t* Kb = Kg + (size_t)bh * SL * DH;
  const bf16_t* Vb = Vg + (size_t)bh * SL * DH;

  // persistent Q B-frags (wave rows l0 + w*16 + lx)
  const bf16_t* Qrow = Qg + ((size_t)bh * SL + l0 + w * 16 + lx) * DH;
  v8bf qf0 = *(const v8bf*)(Qrow + g * 8);
  v8bf qf1 = *(const v8bf*)(Qrow + 32 + g * 8);

  v4f O[4] = {};      // [dt]; C rows = local q g*4+reg, cols = d dt*16+lx
  float suml = 0.f;   // per-lane partial denominator for row lx

  const int vtp = t & 31, vtd = t >> 5;
  const int vmb = b * SL;

  for (int mt = 0; mt < SL / 64; ++mt) {
    const int m0 = mt * 64;
    const bool active  = (mt <= qb);
    const bool partial = (mt == qb);

    if (active) {
      __syncthreads();  // all waves done with previous Vt
      const bf16_t* vsrc = Vb + (size_t)(m0 + 2 * vtp) * DH + vtd * 8;
      const int vm0 = vmask[vmb + m0 + 2 * vtp];
      const int vm1 = vmask[vmb + m0 + 2 * vtp + 1];
      uint4 r0 = *(const uint4*)vsrc;
      uint4 r1 = *(const uint4*)(vsrc + DH);
      const unsigned msk0 = vm0 ? 0xffffffffu : 0u;
      const unsigned msk1 = vm1 ? 0xffffffffu : 0u;
      const unsigned w0[4] = {r0.x & msk0, r0.y & msk0, r0.z & msk0, r0.w & msk0};
      const unsigned w1[4] = {r1.x & msk1, r1.y & msk1, r1.z & msk1, r1.w & msk1};
#pragma unroll
      for (int i = 0; i < 4; ++i) {
        unsigned lo = (w0[i] & 0xffffu) | (w1[i] << 16);
        unsigned hi = (w0[i] >> 16) | (w1[i] & 0xffff0000u);
        *(unsigned*)&Vt[vtd * 8 + 2 * i][2 * vtp]     = lo;
        *(unsigned*)&Vt[vtd * 8 + 2 * i + 1][2 * vtp] = hi;
      }
      __syncthreads();
    }

    // S^T tiles: rows = m (ct*16 + g*4 + reg), cols = q (lx)
    v4f S[4] = {};
#pragma unroll
    for (int ks = 0; ks < 2; ++ks) {
      v8bf kf[4];
#pragma unroll
      for (int ct = 0; ct < 4; ++ct)
        kf[ct] = *(const v8bf*)(Kb + (size_t)(m0 + ct * 16 + lx) * DH +
                                ks * 32 + g * 8);
      const v8bf qf = ks ? qf1 : qf0;
#pragma unroll
      for (int ct = 0; ct < 4; ++ct)
        S[ct] = __builtin_amdgcn_mfma_f32_16x16x32_bf16(kf[ct], qf, S[ct],
                                                        0, 0, 0);
    }

    if (!active) {  // denominator only
#pragma unroll
      for (int ct = 0; ct < 4; ++ct)
#pragma unroll
        for (int reg = 0; reg < 4; ++reg)
          suml += __builtin_amdgcn_exp2f(S[ct][reg]);
    } else if (!partial) {  // fully unmasked: P = e
#pragma unroll
      for (int ct = 0; ct < 4; ++ct) {
        float e0 = __builtin_amdgcn_exp2f(S[ct][0]);
        float e1 = __builtin_amdgcn_exp2f(S[ct][1]);
        float e2 = __builtin_amdgcn_exp2f(S[ct][2]);
        float e3 = __builtin_amdgcn_exp2f(S[ct][3]);
        suml += (e0 + e1) + (e2 + e3);
        uint2 u = {pack_bf16(e0, e1), pack_bf16(e2, e3)};
        *(uint2*)&Ps[w][lx][ct * 16 + g * 4] = u;
      }
    } else {  // diagonal tile: causal select on P, denominator unmasked
      const int l_loc = w * 16 + lx;
#pragma unroll
      for (int ct = 0; ct < 4; ++ct) {
        float e0 = __builtin_amdgcn_exp2f(S[ct][0]);
        float e1 = __builtin_amdgcn_exp2f(S[ct][1]);
        float e2 = __builtin_amdgcn_exp2f(S[ct][2]);
        float e3 = __builtin_amdgcn_exp2f(S[ct][3]);
        suml += (e0 + e1) + (e2 + e3);
        const int mbase = ct * 16 + g * 4;
        float p0 = (mbase + 0 <= l_loc) ? e0 : 0.f;
        float p1 = (mbase + 1 <= l_loc) ? e1 : 0.f;
        float p2 = (mbase + 2 <= l_loc) ? e2 : 0.f;
        float p3 = (mbase + 3 <= l_loc) ? e3 : 0.f;
        uint2 u = {pack_bf16(p0, p1), pack_bf16(p2, p3)};
        *(uint2*)&Ps[w][lx][ct * 16 + g * 4] = u;
      }
    }

    if (active) {  // O += P . V  (Ps wave-private; same-wave LDS ordering)
#pragma unroll
      for (int ks = 0; ks < 2; ++ks) {
        v8bf pf = *(const v8bf*)&Ps[w][lx][ks * 32 + g * 8];
#pragma unroll
        for (int dt = 0; dt < 4; ++dt) {
          v8bf vf = *(const v8bf*)&Vt[dt * 16 + lx][ks * 32 + g * 8];
          O[dt] = __builtin_amdgcn_mfma_f32_16x16x32_bf16(pf, vf, O[dt],
                                                          0, 0, 0);
        }
      }
    }
  }

  // denominator: reduce lane-partials across the 4 g-groups (row = lx)
  suml += __shfl_xor(suml, 16);
  suml += __shfl_xor(suml, 32);

#pragma unroll
  for (int reg = 0; reg < 4; ++reg) {
    const int lg = l0 + w * 16 + g * 4 + reg;
    const float den = __shfl(suml, g * 4 + reg);  // lane with lx == g*4+reg
    const float inv = (float)qmask[b * SL + lg] / den;
#pragma unroll
    for (int dt = 0; dt < 4; ++dt)
      Xout[((size_t)(b * SL + lg)) * NV + h * DH + dt * 16 + lx] =
          O[dt][reg] * inv;
  }
}

// ---------------------------------------------------------------------------
// Residual + LayerNorm over last dim (V=1024). One block per row, 256 threads.
__global__ __launch_bounds__(256)
void ln_kernel(const float* __restrict__ X, const float* __restrict__ query,
               const float* __restrict__ gamma, const float* __restrict__ beta,
               float* __restrict__ out) {
  const int row = blockIdx.x;
  const int t = threadIdx.x;
  const float* xr = X + (size_t)row * NV;
  const float* qr = query + (size_t)row * NV;
  float4 xv = *(const float4*)(xr + t * 4);
  float4 qv = *(const float4*)(qr + t * 4);
  float y[4] = {xv.x + qv.x, xv.y + qv.y, xv.z + qv.z, xv.w + qv.w};
  float s  = y[0] + y[1] + y[2] + y[3];
  float ss = y[0]*y[0] + y[1]*y[1] + y[2]*y[2] + y[3]*y[3];
#pragma unroll
  for (int off = 1; off < 64; off <<= 1) {
    s  += __shfl_xor(s, off);
    ss += __shfl_xor(ss, off);
  }
  __shared__ float ws_s[4], ws_ss[4];
  const int wid = t >> 6;
  if ((t & 63) == 0) { ws_s[wid] = s; ws_ss[wid] = ss; }
  __syncthreads();
  s  = ws_s[0] + ws_s[1] + ws_s[2] + ws_s[3];
  ss = ws_ss[0] + ws_ss[1] + ws_ss[2] + ws_ss[3];
  const float mu   = s * (1.f / NV);
  const float var  = ss * (1.f / NV) - mu * mu;
  const float rstd = rsqrtf(var + LN_EPS);
  float4 gv = *(const float4*)(gamma + t * 4);
  float4 bv = *(const float4*)(beta + t * 4);
  float4 o;
  o.x = gv.x * (y[0] - mu) * rstd + bv.x;
  o.y = gv.y * (y[1] - mu) * rstd + bv.y;
  o.z = gv.z * (y[2] - mu) * rstd + bv.z;
  o.w = gv.w * (y[3] - mu) * rstd + bv.w;
  *(float4*)(out + (size_t)row * NV + t * 4) = o;
}

// ---------------------------------------------------------------------------
extern "C" void kernel_launch(void* const* d_in, const int* in_sizes, int n_in,
                              void* d_out, int out_size, void* d_ws, size_t ws_size,
                              hipStream_t stream) {
  const float* query = (const float*)d_in[0];
  const float* key_t = (const float*)d_in[1];
  const float* value = (const float*)d_in[2];
  const float* Wq    = (const float*)d_in[3];
  const float* Wk    = (const float*)d_in[4];
  const float* Wv    = (const float*)d_in[5];
  const float* gamma = (const float*)d_in[6];
  const float* beta  = (const float*)d_in[7];
  const int*   qmask = (const int*)d_in[8];
  const int*   vmask = (const int*)d_in[9];
  float* out = (float*)d_out;

  const size_t per = (size_t)NB * NH * SL * DH;  // 4,194,304 elements
  bf16_t* Qws = (bf16_t*)d_ws;
  bf16_t* Kws = Qws + per;
  bf16_t* Vws = Kws + per;
  bf16_t* Wtb = Vws + per;  // 3 * 1024*1024 bf16 = 6 MB

  wcvt<<<dim3(16, 16, 3), 256, 0, stream>>>(Wq, Wk, Wv, Wtb);
  proj_mfma<<<dim3(32, 8, 3), 256, 0, stream>>>(query, key_t, value, Wtb,
                                                Qws, Kws, Vws);
  attn_mfma<<<dim3(32, 32), 256, 0, stream>>>(Qws, Kws, Vws, qmask, vmask, out);
  ln_kernel<<<NB * SL, 256, 0, stream>>>(out, query, gamma, beta, out);
}

// Round 4
// 307.684 us; speedup vs baseline: 3.4581x; 1.3208x over previous
//
#include <hip/hip_runtime.h>
#include <math.h>

constexpr int NB = 2;      // batch
constexpr int SL = 2048;   // sequence length
constexpr int NV = 1024;   // model dim
constexpr int NH = 16;     // heads
constexpr int DH = 64;     // head dim
constexpr float LN_EPS = 1e-3f;

typedef __bf16 bf16_t;
typedef __bf16 v8bf __attribute__((ext_vector_type(8)));
typedef float  v4f  __attribute__((ext_vector_type(4)));

__device__ __forceinline__ v8bf cvt8(float4 a, float4 b) {
  v8bf v;
  v[0] = (bf16_t)a.x; v[1] = (bf16_t)a.y; v[2] = (bf16_t)a.z; v[3] = (bf16_t)a.w;
  v[4] = (bf16_t)b.x; v[5] = (bf16_t)b.y; v[6] = (bf16_t)b.z; v[7] = (bf16_t)b.w;
  return v;
}
__device__ __forceinline__ unsigned pack_bf16(float a, float b) {
  unsigned short ua = __builtin_bit_cast(unsigned short, (bf16_t)a);
  unsigned short ub = __builtin_bit_cast(unsigned short, (bf16_t)b);
  return (unsigned)ua | ((unsigned)ub << 16);
}
// async global->LDS, 16B/lane; LDS dest = wave-uniform base + lane*16.
__device__ __forceinline__ void async_cp16(const void* g, void* l) {
  __builtin_amdgcn_global_load_lds(
      (const __attribute__((address_space(1))) unsigned int*)g,
      (__attribute__((address_space(3))) unsigned int*)l, 16, 0, 0);
}

// ---------------------------------------------------------------------------
// W transpose+convert: W[h][v][d] fp32 -> Wt[z][n=h*64+d][v] bf16.
// Scale (1/8 * log2e) folded into Wq (softmax then uses exp2 directly).
__global__ __launch_bounds__(256)
void wcvt(const float* __restrict__ Wq, const float* __restrict__ Wk,
          const float* __restrict__ Wv, bf16_t* __restrict__ Wt) {
  __shared__ float ls[64][65];
  const int z = blockIdx.z;
  const float* W = z == 0 ? Wq : (z == 1 ? Wk : Wv);
  const float sc = z == 0 ? 0.125f * 1.44269504f : 1.0f;
  const int h = blockIdx.y, v0 = blockIdx.x * 64;
  const int t = threadIdx.x;
  const int rr = t >> 4, c4 = t & 15;
  const float* src = W + ((size_t)h * NV + v0) * DH;
#pragma unroll
  for (int it = 0; it < 4; ++it) {
    float4 f = *(const float4*)(src + (size_t)(rr + it * 16) * DH + c4 * 4);
    ls[rr + it * 16][c4 * 4 + 0] = f.x;
    ls[rr + it * 16][c4 * 4 + 1] = f.y;
    ls[rr + it * 16][c4 * 4 + 2] = f.z;
    ls[rr + it * 16][c4 * 4 + 3] = f.w;
  }
  __syncthreads();
  const int dd = t >> 2, vq = t & 3;
  bf16_t tmp[16];
#pragma unroll
  for (int i = 0; i < 16; ++i) tmp[i] = (bf16_t)(ls[vq * 16 + i][dd] * sc);
  bf16_t* dst = Wt + ((size_t)z * NV + h * 64 + dd) * NV + v0 + vq * 16;
  *(v8bf*)dst = *(v8bf*)&tmp[0];
  *(v8bf*)(dst + 8) = *(v8bf*)&tmp[8];
}

// ---------------------------------------------------------------------------
// Projection GEMM, m97-style: global_load_lds staging (coalesced, XOR-swizzled
// LDS layout), fp32 A converted to bf16 in-register after ds_read.
// acc[m][n] = sum_k A[m][k] * Wt[n][k].  Tile 128x128, BK=64.
// Grid (32, 8, 3); 256 threads = 4 waves in 2x2, wave tile 64x64.
__global__ __launch_bounds__(256, 3)
void proj_mfma(const float* __restrict__ A0, const float* __restrict__ A1,
               const float* __restrict__ A2, const bf16_t* __restrict__ Wtb,
               bf16_t* __restrict__ O0, bf16_t* __restrict__ O1,
               bf16_t* __restrict__ O2) {
  // As: 128 rows x 64 fp32 (256B row = 16 chunks of 16B), chunk swizzle c^(r&7)
  // Ws: 128 rows x 64 bf16 (128B row = 8 chunks of 16B),  chunk swizzle c^(r&7)
  __shared__ __align__(16) float  As[128 * 64];
  __shared__ __align__(16) bf16_t Wsh[128 * 64];

  const int z = blockIdx.z;
  const float*  A   = z == 0 ? A0 : (z == 1 ? A1 : A2);
  bf16_t*       out = z == 0 ? O0 : (z == 1 ? O1 : O2);
  const bf16_t* W   = Wtb + (size_t)z * NV * NV;

  const int t = threadIdx.x, w = t >> 6, lane = t & 63;
  const int g = lane >> 4, lx = lane & 15;
  const int m0 = blockIdx.x * 128, n0 = blockIdx.y * 128;
  const int rbase = (w >> 1) * 64, cbase = (w & 1) * 64;

  const int ra_off = lane >> 4;   // A staging: 4 rows/instr
  const int ca_l   = lane & 15;
  const int rw_off = lane >> 3;   // W staging: 8 rows/instr
  const int cw_l   = lane & 7;

  v4f acc[4][4] = {};

  for (int k0 = 0; k0 < NV; k0 += 64) {
    __syncthreads();
    // stage A tile: 8 instrs/wave, each 4 full 256B rows (perfectly coalesced)
#pragma unroll
    for (int s = 0; s < 8; ++s) {
      const int ra  = w * 32 + s * 4 + ra_off;
      const int cga = ca_l ^ (ra & 7);
      async_cp16(A + (size_t)(m0 + ra) * NV + k0 + cga * 4,
                 (char*)As + (w * 32 + s * 4) * 256);
    }
    // stage W tile: 4 instrs/wave, each 8 full 128B rows
#pragma unroll
    for (int s = 0; s < 4; ++s) {
      const int rw  = w * 32 + s * 8 + rw_off;
      const int cgw = cw_l ^ (rw_off & 7);
      async_cp16(W + (size_t)(n0 + rw) * NV + k0 + cgw * 8,
                 (char*)Wsh + (w * 32 + s * 8) * 128);
    }
    __syncthreads();
#pragma unroll
    for (int ks = 0; ks < 2; ++ks) {
      v8bf af[4], bfr[4];
#pragma unroll
      for (int rt = 0; rt < 4; ++rt) {
        const int row = rbase + rt * 16 + lx;
        const int sw = lx & 7;
        const int c0 = ks * 8 + g * 2;
        float4 f0 = *(const float4*)((const char*)As + row * 256 + ((c0    ) ^ sw) * 16);
        float4 f1 = *(const float4*)((const char*)As + row * 256 + ((c0 + 1) ^ sw) * 16);
        af[rt] = cvt8(f0, f1);
      }
#pragma unroll
      for (int ct = 0; ct < 4; ++ct) {
        const int row = cbase + ct * 16 + lx;
        const int c = ks * 4 + g;
        bfr[ct] = *(const v8bf*)((const char*)Wsh + row * 128 + (c ^ (lx & 7)) * 16);
      }
#pragma unroll
      for (int rt = 0; rt < 4; ++rt)
#pragma unroll
        for (int ct = 0; ct < 4; ++ct)
          acc[rt][ct] = __builtin_amdgcn_mfma_f32_16x16x32_bf16(
              af[rt], bfr[ct], acc[rt][ct], 0, 0, 0);
    }
  }

  // store bf16. C-layout: row=(lane>>4)*4+reg, col=lane&15.
#pragma unroll
  for (int rt = 0; rt < 4; ++rt) {
#pragma unroll
    for (int reg = 0; reg < 4; ++reg) {
      const int row = m0 + rbase + rt * 16 + g * 4 + reg;
      const int b = row >> 11, l = row & (SL - 1);
#pragma unroll
      for (int ct = 0; ct < 4; ++ct) {
        const int n = n0 + cbase + ct * 16 + lx;
        const int h = n >> 6, d = n & 63;
        out[((size_t)(b * NH + h) * SL + l) * DH + d] = (bf16_t)acc[rt][ct][reg];
      }
    }
  }
}

// ---------------------------------------------------------------------------
// Fused attention, bf16 MFMA, cross-iteration register prefetch of K and V.
// Reference semantics: softmax denominator over ALL m (unmasked); numerator
// (PV) masked by tril & vm; qm applied at epilogue. exp2, no max-tracking
// (scores ~N(0,1); log2e folded into Q via wcvt).
// Block: 64 q-rows, 4 waves x 16 rows. Grid (SL/64, NB*NH).
__global__ __launch_bounds__(256, 4)
void attn_mfma(const bf16_t* __restrict__ Qg, const bf16_t* __restrict__ Kg,
               const bf16_t* __restrict__ Vg, const int* __restrict__ qmask,
               const int* __restrict__ vmask, float* __restrict__ Xout) {
  __shared__ bf16_t Vt[2][64][72];  // V^T[d][m], vm-masked, double-buffered
  __shared__ bf16_t Ps[4][16][72];  // per-wave P strip [l][m]

  const int t = threadIdx.x, w = t >> 6, lane = t & 63;
  const int g = lane >> 4, lx = lane & 15;
  const int bh = blockIdx.y, b = bh >> 4, h = bh & 15;
  const int qb = blockIdx.x, l0 = qb * 64;
  const int NT = SL / 64;

  const bf16_t* Kb = Kg + (size_t)bh * SL * DH;
  const bf16_t* Vb = Vg + (size_t)bh * SL * DH;

  // persistent Q B-frags (wave rows l0 + w*16 + lx)
  const bf16_t* Qrow = Qg + ((size_t)bh * SL + l0 + w * 16 + lx) * DH;
  v8bf qf0 = *(const v8bf*)(Qrow + g * 8);
  v8bf qf1 = *(const v8bf*)(Qrow + 32 + g * 8);

  v4f O[4] = {};
  float suml = 0.f;

  const int vtp = t & 31, vtd = t >> 5, vmb = b * SL;

  v8bf kf[2][4];
  auto loadK = [&](int mb) {
#pragma unroll
    for (int ks = 0; ks < 2; ++ks)
#pragma unroll
      for (int ct = 0; ct < 4; ++ct)
        kf[ks][ct] = *(const v8bf*)(Kb + (size_t)(mb + ct * 16 + lx) * DH +
                                    ks * 32 + g * 8);
  };
  uint4 vr0, vr1;
  unsigned vmsk0, vmsk1;
  auto loadV = [&](int mb) {
    const bf16_t* vsrc = Vb + (size_t)(mb + 2 * vtp) * DH + vtd * 8;
    vmsk0 = vmask[vmb + mb + 2 * vtp]     ? 0xffffffffu : 0u;
    vmsk1 = vmask[vmb + mb + 2 * vtp + 1] ? 0xffffffffu : 0u;
    vr0 = *(const uint4*)vsrc;
    vr1 = *(const uint4*)(vsrc + DH);
  };

  loadK(0);
  loadV(0);

  // ---- active tiles (mt <= qb): full S, P, PV ----
  for (int mt = 0; mt <= qb; ++mt) {
    const int m0 = mt * 64, pb = mt & 1;
    {  // masked transpose-write of prefetched V rows into Vt[pb]
      const unsigned w0[4] = {vr0.x & vmsk0, vr0.y & vmsk0, vr0.z & vmsk0, vr0.w & vmsk0};
      const unsigned w1[4] = {vr1.x & vmsk1, vr1.y & vmsk1, vr1.z & vmsk1, vr1.w & vmsk1};
#pragma unroll
      for (int i = 0; i < 4; ++i) {
        unsigned lo = (w0[i] & 0xffffu) | (w1[i] << 16);
        unsigned hi = (w0[i] >> 16) | (w1[i] & 0xffff0000u);
        *(unsigned*)&Vt[pb][vtd * 8 + 2 * i][2 * vtp]     = lo;
        *(unsigned*)&Vt[pb][vtd * 8 + 2 * i + 1][2 * vtp] = hi;
      }
    }
    if (mt < qb) loadV(m0 + 64);  // prefetch next V while barrier drains
    __syncthreads();

    // S^T strip: rows = m (ct*16+g*4+reg), cols = q (lx)
    v4f S[4] = {};
#pragma unroll
    for (int ks = 0; ks < 2; ++ks) {
      const v8bf qf = ks ? qf1 : qf0;
#pragma unroll
      for (int ct = 0; ct < 4; ++ct)
        S[ct] = __builtin_amdgcn_mfma_f32_16x16x32_bf16(kf[ks][ct], qf, S[ct],
                                                        0, 0, 0);
    }
    if (mt + 1 < NT) loadK(m0 + 64);  // prefetch next K during softmax/PV

    const bool diag = (mt == qb);
    if (!diag) {
#pragma unroll
      for (int ct = 0; ct < 4; ++ct) {
        float e0 = __builtin_amdgcn_exp2f(S[ct][0]);
        float e1 = __builtin_amdgcn_exp2f(S[ct][1]);
        float e2 = __builtin_amdgcn_exp2f(S[ct][2]);
        float e3 = __builtin_amdgcn_exp2f(S[ct][3]);
        suml += (e0 + e1) + (e2 + e3);
        uint2 u = {pack_bf16(e0, e1), pack_bf16(e2, e3)};
        *(uint2*)&Ps[w][lx][ct * 16 + g * 4] = u;
      }
    } else {
      const int l_loc = w * 16 + lx;
#pragma unroll
      for (int ct = 0; ct < 4; ++ct) {
        float e0 = __builtin_amdgcn_exp2f(S[ct][0]);
        float e1 = __builtin_amdgcn_exp2f(S[ct][1]);
        float e2 = __builtin_amdgcn_exp2f(S[ct][2]);
        float e3 = __builtin_amdgcn_exp2f(S[ct][3]);
        suml += (e0 + e1) + (e2 + e3);
        const int mb = ct * 16 + g * 4;
        float p0 = (mb + 0 <= l_loc) ? e0 : 0.f;
        float p1 = (mb + 1 <= l_loc) ? e1 : 0.f;
        float p2 = (mb + 2 <= l_loc) ? e2 : 0.f;
        float p3 = (mb + 3 <= l_loc) ? e3 : 0.f;
        uint2 u = {pack_bf16(p0, p1), pack_bf16(p2, p3)};
        *(uint2*)&Ps[w][lx][ct * 16 + g * 4] = u;
      }
    }

    // O += P . V  (Ps wave-private: same-wave LDS ordering suffices)
#pragma unroll
    for (int ks = 0; ks < 2; ++ks) {
      v8bf pf = *(const v8bf*)&Ps[w][lx][ks * 32 + g * 8];
#pragma unroll
      for (int dt = 0; dt < 4; ++dt) {
        v8bf vf = *(const v8bf*)&Vt[pb][dt * 16 + lx][ks * 32 + g * 8];
        O[dt] = __builtin_amdgcn_mfma_f32_16x16x32_bf16(pf, vf, O[dt], 0, 0, 0);
      }
    }
  }

  // ---- future tiles (mt > qb): denominator only, no barriers ----
  for (int mt = qb + 1; mt < NT; ++mt) {
    v4f S[4] = {};
#pragma unroll
    for (int ks = 0; ks < 2; ++ks) {
      const v8bf qf = ks ? qf1 : qf0;
#pragma unroll
      for (int ct = 0; ct < 4; ++ct)
        S[ct] = __builtin_amdgcn_mfma_f32_16x16x32_bf16(kf[ks][ct], qf, S[ct],
                                                        0, 0, 0);
    }
    if (mt + 1 < NT) loadK(mt * 64 + 64);
#pragma unroll
    for (int ct = 0; ct < 4; ++ct)
#pragma unroll
      for (int r = 0; r < 4; ++r)
        suml += __builtin_amdgcn_exp2f(S[ct][r]);
  }

  // reduce lane-partial denominators across the 4 g-groups (row = lx)
  suml += __shfl_xor(suml, 16);
  suml += __shfl_xor(suml, 32);

#pragma unroll
  for (int reg = 0; reg < 4; ++reg) {
    const int lg = l0 + w * 16 + g * 4 + reg;
    const float den = __shfl(suml, g * 4 + reg);
    const float inv = (float)qmask[b * SL + lg] / den;
#pragma unroll
    for (int dt = 0; dt < 4; ++dt)
      Xout[((size_t)(b * SL + lg)) * NV + h * DH + dt * 16 + lx] =
          O[dt][reg] * inv;
  }
}

// ---------------------------------------------------------------------------
// Residual + LayerNorm over last dim (V=1024). One block per row, 256 threads.
__global__ __launch_bounds__(256)
void ln_kernel(const float* __restrict__ X, const float* __restrict__ query,
               const float* __restrict__ gamma, const float* __restrict__ beta,
               float* __restrict__ out) {
  const int row = blockIdx.x;
  const int t = threadIdx.x;
  const float* xr = X + (size_t)row * NV;
  const float* qr = query + (size_t)row * NV;
  float4 xv = *(const float4*)(xr + t * 4);
  float4 qv = *(const float4*)(qr + t * 4);
  float y[4] = {xv.x + qv.x, xv.y + qv.y, xv.z + qv.z, xv.w + qv.w};
  float s  = y[0] + y[1] + y[2] + y[3];
  float ss = y[0]*y[0] + y[1]*y[1] + y[2]*y[2] + y[3]*y[3];
#pragma unroll
  for (int off = 1; off < 64; off <<= 1) {
    s  += __shfl_xor(s, off);
    ss += __shfl_xor(ss, off);
  }
  __shared__ float ws_s[4], ws_ss[4];
  const int wid = t >> 6;
  if ((t & 63) == 0) { ws_s[wid] = s; ws_ss[wid] = ss; }
  __syncthreads();
  s  = ws_s[0] + ws_s[1] + ws_s[2] + ws_s[3];
  ss = ws_ss[0] + ws_ss[1] + ws_ss[2] + ws_ss[3];
  const float mu   = s * (1.f / NV);
  const float var  = ss * (1.f / NV) - mu * mu;
  const float rstd = rsqrtf(var + LN_EPS);
  float4 gv = *(const float4*)(gamma + t * 4);
  float4 bv = *(const float4*)(beta + t * 4);
  float4 o;
  o.x = gv.x * (y[0] - mu) * rstd + bv.x;
  o.y = gv.y * (y[1] - mu) * rstd + bv.y;
  o.z = gv.z * (y[2] - mu) * rstd + bv.z;
  o.w = gv.w * (y[3] - mu) * rstd + bv.w;
  *(float4*)(out + (size_t)row * NV + t * 4) = o;
}

// ---------------------------------------------------------------------------
extern "C" void kernel_launch(void* const* d_in, const int* in_sizes, int n_in,
                              void* d_out, int out_size, void* d_ws, size_t ws_size,
                              hipStream_t stream) {
  const float* query = (const float*)d_in[0];
  const float* key_t = (const float*)d_in[1];
  const float* value = (const float*)d_in[2];
  const float* Wq    = (const float*)d_in[3];
  const float* Wk    = (const float*)d_in[4];
  const float* Wv    = (const float*)d_in[5];
  const float* gamma = (const float*)d_in[6];
  const float* beta  = (const float*)d_in[7];
  const int*   qmask = (const int*)d_in[8];
  const int*   vmask = (const int*)d_in[9];
  float* out = (float*)d_out;

  const size_t per = (size_t)NB * NH * SL * DH;  // 4,194,304 elements
  bf16_t* Qws = (bf16_t*)d_ws;
  bf16_t* Kws = Qws + per;
  bf16_t* Vws = Kws + per;
  bf16_t* Wtb = Vws + per;  // 3 * 1024*1024 bf16 = 6 MB

  wcvt<<<dim3(16, 16, 3), 256, 0, stream>>>(Wq, Wk, Wv, Wtb);
  proj_mfma<<<dim3(32, 8, 3), 256, 0, stream>>>(query, key_t, value, Wtb,
                                                Qws, Kws, Vws);
  attn_mfma<<<dim3(32, 32), 256, 0, stream>>>(Qws, Kws, Vws, qmask, vmask, out);
  ln_kernel<<<NB * SL, 256, 0, stream>>>(out, query, gamma, beta, out);
}

// Round 5
// 232.171 us; speedup vs baseline: 4.5829x; 1.3252x over previous
//
#include <hip/hip_runtime.h>
#include <math.h>

constexpr int NB = 2;      // batch
constexpr int SL = 2048;   // sequence length
constexpr int NV = 1024;   // model dim
constexpr int NH = 16;     // heads
constexpr int DH = 64;     // head dim
constexpr int NT = SL / 64;
constexpr float LN_EPS = 1e-3f;

typedef __bf16 bf16_t;
typedef __bf16 v8bf __attribute__((ext_vector_type(8)));
typedef float  v4f  __attribute__((ext_vector_type(4)));

__device__ __forceinline__ v8bf cvt8(float4 a, float4 b) {
  v8bf v;
  v[0] = (bf16_t)a.x; v[1] = (bf16_t)a.y; v[2] = (bf16_t)a.z; v[3] = (bf16_t)a.w;
  v[4] = (bf16_t)b.x; v[5] = (bf16_t)b.y; v[6] = (bf16_t)b.z; v[7] = (bf16_t)b.w;
  return v;
}
__device__ __forceinline__ unsigned pack_bf16(float a, float b) {
  unsigned short ua = __builtin_bit_cast(unsigned short, (bf16_t)a);
  unsigned short ub = __builtin_bit_cast(unsigned short, (bf16_t)b);
  return (unsigned)ua | ((unsigned)ub << 16);
}
// async global->LDS, 16B/lane; LDS dest = wave-uniform base + lane*16.
__device__ __forceinline__ void async_cp16(const void* g, void* l) {
  __builtin_amdgcn_global_load_lds(
      (const __attribute__((address_space(1))) unsigned int*)g,
      (__attribute__((address_space(3))) unsigned int*)l, 16, 0, 0);
}

// ---------------------------------------------------------------------------
// W transpose+convert: W[h][v][d] fp32 -> Wt[z][n=h*64+d][v] bf16.
// Scale (1/8 * log2e) folded into Wq (softmax then uses exp2 directly).
__global__ __launch_bounds__(256)
void wcvt(const float* __restrict__ Wq, const float* __restrict__ Wk,
          const float* __restrict__ Wv, bf16_t* __restrict__ Wt) {
  __shared__ float ls[64][65];
  const int z = blockIdx.z;
  const float* W = z == 0 ? Wq : (z == 1 ? Wk : Wv);
  const float sc = z == 0 ? 0.125f * 1.44269504f : 1.0f;
  const int h = blockIdx.y, v0 = blockIdx.x * 64;
  const int t = threadIdx.x;
  const int rr = t >> 4, c4 = t & 15;
  const float* src = W + ((size_t)h * NV + v0) * DH;
#pragma unroll
  for (int it = 0; it < 4; ++it) {
    float4 f = *(const float4*)(src + (size_t)(rr + it * 16) * DH + c4 * 4);
    ls[rr + it * 16][c4 * 4 + 0] = f.x;
    ls[rr + it * 16][c4 * 4 + 1] = f.y;
    ls[rr + it * 16][c4 * 4 + 2] = f.z;
    ls[rr + it * 16][c4 * 4 + 3] = f.w;
  }
  __syncthreads();
  const int dd = t >> 2, vq = t & 3;
  bf16_t tmp[16];
#pragma unroll
  for (int i = 0; i < 16; ++i) tmp[i] = (bf16_t)(ls[vq * 16 + i][dd] * sc);
  bf16_t* dst = Wt + ((size_t)z * NV + h * 64 + dd) * NV + v0 + vq * 16;
  *(v8bf*)dst = *(v8bf*)&tmp[0];
  *(v8bf*)(dst + 8) = *(v8bf*)&tmp[8];
}

// ---------------------------------------------------------------------------
// Projection GEMM, m97-style: global_load_lds staging (coalesced, XOR-swizzled
// LDS layout), fp32 A converted to bf16 in-register after ds_read.
// acc[m][n] = sum_k A[m][k] * Wt[n][k].  Tile 128x128, BK=64.
// Grid (32, 8, 3); 256 threads = 4 waves in 2x2, wave tile 64x64.
__global__ __launch_bounds__(256, 3)
void proj_mfma(const float* __restrict__ A0, const float* __restrict__ A1,
               const float* __restrict__ A2, const bf16_t* __restrict__ Wtb,
               bf16_t* __restrict__ O0, bf16_t* __restrict__ O1,
               bf16_t* __restrict__ O2) {
  __shared__ __align__(16) float  As[128 * 64];
  __shared__ __align__(16) bf16_t Wsh[128 * 64];

  const int z = blockIdx.z;
  const float*  A   = z == 0 ? A0 : (z == 1 ? A1 : A2);
  bf16_t*       out = z == 0 ? O0 : (z == 1 ? O1 : O2);
  const bf16_t* W   = Wtb + (size_t)z * NV * NV;

  const int t = threadIdx.x, w = t >> 6, lane = t & 63;
  const int g = lane >> 4, lx = lane & 15;
  const int m0 = blockIdx.x * 128, n0 = blockIdx.y * 128;
  const int rbase = (w >> 1) * 64, cbase = (w & 1) * 64;

  const int ra_off = lane >> 4;   // A staging: 4 rows/instr
  const int ca_l   = lane & 15;
  const int rw_off = lane >> 3;   // W staging: 8 rows/instr
  const int cw_l   = lane & 7;

  v4f acc[4][4] = {};

  for (int k0 = 0; k0 < NV; k0 += 64) {
    __syncthreads();
#pragma unroll
    for (int s = 0; s < 8; ++s) {
      const int ra  = w * 32 + s * 4 + ra_off;
      const int cga = ca_l ^ (ra & 7);
      async_cp16(A + (size_t)(m0 + ra) * NV + k0 + cga * 4,
                 (char*)As + (w * 32 + s * 4) * 256);
    }
#pragma unroll
    for (int s = 0; s < 4; ++s) {
      const int rw  = w * 32 + s * 8 + rw_off;
      const int cgw = cw_l ^ (rw_off & 7);
      async_cp16(W + (size_t)(n0 + rw) * NV + k0 + cgw * 8,
                 (char*)Wsh + (w * 32 + s * 8) * 128);
    }
    __syncthreads();
#pragma unroll
    for (int ks = 0; ks < 2; ++ks) {
      v8bf af[4], bfr[4];
#pragma unroll
      for (int rt = 0; rt < 4; ++rt) {
        const int row = rbase + rt * 16 + lx;
        const int sw = lx & 7;
        const int c0 = ks * 8 + g * 2;
        float4 f0 = *(const float4*)((const char*)As + row * 256 + ((c0    ) ^ sw) * 16);
        float4 f1 = *(const float4*)((const char*)As + row * 256 + ((c0 + 1) ^ sw) * 16);
        af[rt] = cvt8(f0, f1);
      }
#pragma unroll
      for (int ct = 0; ct < 4; ++ct) {
        const int row = cbase + ct * 16 + lx;
        const int c = ks * 4 + g;
        bfr[ct] = *(const v8bf*)((const char*)Wsh + row * 128 + (c ^ (lx & 7)) * 16);
      }
#pragma unroll
      for (int rt = 0; rt < 4; ++rt)
#pragma unroll
        for (int ct = 0; ct < 4; ++ct)
          acc[rt][ct] = __builtin_amdgcn_mfma_f32_16x16x32_bf16(
              af[rt], bfr[ct], acc[rt][ct], 0, 0, 0);
    }
  }

#pragma unroll
  for (int rt = 0; rt < 4; ++rt) {
#pragma unroll
    for (int reg = 0; reg < 4; ++reg) {
      const int row = m0 + rbase + rt * 16 + g * 4 + reg;
      const int b = row >> 11, l = row & (SL - 1);
#pragma unroll
      for (int ct = 0; ct < 4; ++ct) {
        const int n = n0 + cbase + ct * 16 + lx;
        const int h = n >> 6, d = n & 63;
        out[((size_t)(b * NH + h) * SL + l) * DH + d] = (bf16_t)acc[rt][ct][reg];
      }
    }
  }
}

// ---------------------------------------------------------------------------
// Fused attention. Reference semantics: softmax denominator over ALL m
// (unmasked); PV numerator masked by tril & vm; qm at epilogue. exp2, no
// max-tracking (scores ~N(0,1); log2e folded into Q via wcvt).
// K tiles staged once per block into double-buffered LDS via global_load_lds
// (coalesced, XOR-swizzled); async issued after the barrier so the next
// barrier drains an already-landed load. One barrier per tile.
// XCD swizzle: all 32 q-blocks of a bh map to the same XCD (id%8 const).
// Block: 64 q-rows, 4 waves x 16 rows. Grid 1024 (1D).
__global__ __launch_bounds__(256, 3)
void attn_mfma(const bf16_t* __restrict__ Qg, const bf16_t* __restrict__ Kg,
               const bf16_t* __restrict__ Vg, const int* __restrict__ qmask,
               const int* __restrict__ vmask, float* __restrict__ Xout) {
  // kbuf: 64 rows x 128B (8 chunks of 16B), chunk c stored at slot c^(r&7).
  __shared__ __align__(16) bf16_t kbuf[2][64 * 64];
  __shared__ bf16_t Vt[2][64][72];  // V^T[d][m], vm-masked, double-buffered
  __shared__ bf16_t Ps[4][16][72];  // per-wave P strip [l][m]

  const int id = blockIdx.x;
  const int bh = (id & 7) | ((id >> 8) << 3);  // same-XCD for fixed bh
  const int qb = (id >> 3) & 31;
  const int t = threadIdx.x, w = t >> 6, lane = t & 63;
  const int g = lane >> 4, lx = lane & 15;
  const int b = bh >> 4, h = bh & 15;
  const int l0 = qb * 64;

  const bf16_t* Kb = Kg + (size_t)bh * SL * DH;
  const bf16_t* Vb = Vg + (size_t)bh * SL * DH;

  // persistent Q B-frags (wave rows l0 + w*16 + lx)
  const bf16_t* Qrow = Qg + ((size_t)bh * SL + l0 + w * 16 + lx) * DH;
  v8bf qf0 = *(const v8bf*)(Qrow + g * 8);
  v8bf qf1 = *(const v8bf*)(Qrow + 32 + g * 8);

  v4f O[4] = {};
  float suml = 0.f;

  const int vtp = t & 31, vtd = t >> 5, vmb = b * SL;

  // K staging: wave w, instr s covers rows [w*16+s*8, +8); lane l -> row
  // w*16+s*8+l/8, slot l%8 (= source chunk (l%8)^(row&7)).
  const int kr_off = lane >> 3;          // row within 8-row group
  const int ks_l   = lane & 7;           // dest slot
  auto stageK = [&](int mb, int buf) {
#pragma unroll
    for (int s = 0; s < 2; ++s) {
      const int r = w * 16 + s * 8 + kr_off;
      const int c = ks_l ^ (r & 7);
      async_cp16(Kb + (size_t)(mb + r) * DH + c * 8,
                 (char*)kbuf[buf] + (w * 16 + s * 8) * 128);
    }
  };
  // K frag read from swizzled LDS
  auto readK = [&](int buf, int ks, int ct) -> v8bf {
    const int rr = ct * 16 + lx;
    const int slot = (ks * 4 + g) ^ (lx & 7);
    return *(const v8bf*)((const char*)kbuf[buf] + rr * 128 + slot * 16);
  };

  uint4 vr0, vr1;
  unsigned vmsk0, vmsk1;
  auto loadV = [&](int mb) {
    const bf16_t* vsrc = Vb + (size_t)(mb + 2 * vtp) * DH + vtd * 8;
    vmsk0 = vmask[vmb + mb + 2 * vtp]     ? 0xffffffffu : 0u;
    vmsk1 = vmask[vmb + mb + 2 * vtp + 1] ? 0xffffffffu : 0u;
    vr0 = *(const uint4*)vsrc;
    vr1 = *(const uint4*)(vsrc + DH);
  };

  stageK(0, 0);
  loadV(0);

  // ---- active tiles (mt <= qb): full S, P, PV ----
  for (int mt = 0; mt <= qb; ++mt) {
    const int m0 = mt * 64, pb = mt & 1;
    {  // masked transpose-write of prefetched V rows into Vt[pb]
      const unsigned w0[4] = {vr0.x & vmsk0, vr0.y & vmsk0, vr0.z & vmsk0, vr0.w & vmsk0};
      const unsigned w1[4] = {vr1.x & vmsk1, vr1.y & vmsk1, vr1.z & vmsk1, vr1.w & vmsk1};
#pragma unroll
      for (int i = 0; i < 4; ++i) {
        unsigned lo = (w0[i] & 0xffffu) | (w1[i] << 16);
        unsigned hi = (w0[i] >> 16) | (w1[i] & 0xffff0000u);
        *(unsigned*)&Vt[pb][vtd * 8 + 2 * i][2 * vtp]     = lo;
        *(unsigned*)&Vt[pb][vtd * 8 + 2 * i + 1][2 * vtp] = hi;
      }
    }
    __syncthreads();  // Vt[pb] visible; async K for tile mt drained
    if (mt + 1 < NT) stageK(m0 + 64, pb ^ 1);  // lands by next barrier
    if (mt < qb) loadV(m0 + 64);

    // S^T strip: rows = m (ct*16+g*4+reg), cols = q (lx)
    v4f S[4] = {};
#pragma unroll
    for (int ks = 0; ks < 2; ++ks) {
      const v8bf qf = ks ? qf1 : qf0;
#pragma unroll
      for (int ct = 0; ct < 4; ++ct)
        S[ct] = __builtin_amdgcn_mfma_f32_16x16x32_bf16(readK(pb, ks, ct), qf,
                                                        S[ct], 0, 0, 0);
    }

    const bool diag = (mt == qb);
    if (!diag) {
#pragma unroll
      for (int ct = 0; ct < 4; ++ct) {
        float e0 = __builtin_amdgcn_exp2f(S[ct][0]);
        float e1 = __builtin_amdgcn_exp2f(S[ct][1]);
        float e2 = __builtin_amdgcn_exp2f(S[ct][2]);
        float e3 = __builtin_amdgcn_exp2f(S[ct][3]);
        suml += (e0 + e1) + (e2 + e3);
        uint2 u = {pack_bf16(e0, e1), pack_bf16(e2, e3)};
        *(uint2*)&Ps[w][lx][ct * 16 + g * 4] = u;
      }
    } else {
      const int l_loc = w * 16 + lx;
#pragma unroll
      for (int ct = 0; ct < 4; ++ct) {
        float e0 = __builtin_amdgcn_exp2f(S[ct][0]);
        float e1 = __builtin_amdgcn_exp2f(S[ct][1]);
        float e2 = __builtin_amdgcn_exp2f(S[ct][2]);
        float e3 = __builtin_amdgcn_exp2f(S[ct][3]);
        suml += (e0 + e1) + (e2 + e3);
        const int mb = ct * 16 + g * 4;
        float p0 = (mb + 0 <= l_loc) ? e0 : 0.f;
        float p1 = (mb + 1 <= l_loc) ? e1 : 0.f;
        float p2 = (mb + 2 <= l_loc) ? e2 : 0.f;
        float p3 = (mb + 3 <= l_loc) ? e3 : 0.f;
        uint2 u = {pack_bf16(p0, p1), pack_bf16(p2, p3)};
        *(uint2*)&Ps[w][lx][ct * 16 + g * 4] = u;
      }
    }

    // O += P . V  (Ps wave-private: same-wave LDS ordering suffices)
#pragma unroll
    for (int ks = 0; ks < 2; ++ks) {
      v8bf pf = *(const v8bf*)&Ps[w][lx][ks * 32 + g * 8];
#pragma unroll
      for (int dt = 0; dt < 4; ++dt) {
        v8bf vf = *(const v8bf*)&Vt[pb][dt * 16 + lx][ks * 32 + g * 8];
        O[dt] = __builtin_amdgcn_mfma_f32_16x16x32_bf16(pf, vf, O[dt], 0, 0, 0);
      }
    }
  }

  // ---- future tiles (mt > qb): denominator only (uniform trip count) ----
  for (int mt = qb + 1; mt < NT; ++mt) {
    const int pb = mt & 1;
    __syncthreads();  // async K for tile mt drained
    if (mt + 1 < NT) stageK(mt * 64 + 64, pb ^ 1);
    v4f S[4] = {};
#pragma unroll
    for (int ks = 0; ks < 2; ++ks) {
      const v8bf qf = ks ? qf1 : qf0;
#pragma unroll
      for (int ct = 0; ct < 4; ++ct)
        S[ct] = __builtin_amdgcn_mfma_f32_16x16x32_bf16(readK(pb, ks, ct), qf,
                                                        S[ct], 0, 0, 0);
    }
#pragma unroll
    for (int ct = 0; ct < 4; ++ct)
#pragma unroll
      for (int r = 0; r < 4; ++r)
        suml += __builtin_amdgcn_exp2f(S[ct][r]);
  }

  // reduce lane-partial denominators across the 4 g-groups (row = lx)
  suml += __shfl_xor(suml, 16);
  suml += __shfl_xor(suml, 32);

#pragma unroll
  for (int reg = 0; reg < 4; ++reg) {
    const int lg = l0 + w * 16 + g * 4 + reg;
    const float den = __shfl(suml, g * 4 + reg);
    const float inv = (float)qmask[b * SL + lg] / den;
#pragma unroll
    for (int dt = 0; dt < 4; ++dt)
      Xout[((size_t)(b * SL + lg)) * NV + h * DH + dt * 16 + lx] =
          O[dt][reg] * inv;
  }
}

// ---------------------------------------------------------------------------
// Residual + LayerNorm over last dim (V=1024). One block per row, 256 threads.
__global__ __launch_bounds__(256)
void ln_kernel(const float* __restrict__ X, const float* __restrict__ query,
               const float* __restrict__ gamma, const float* __restrict__ beta,
               float* __restrict__ out) {
  const int row = blockIdx.x;
  const int t = threadIdx.x;
  const float* xr = X + (size_t)row * NV;
  const float* qr = query + (size_t)row * NV;
  float4 xv = *(const float4*)(xr + t * 4);
  float4 qv = *(const float4*)(qr + t * 4);
  float y[4] = {xv.x + qv.x, xv.y + qv.y, xv.z + qv.z, xv.w + qv.w};
  float s  = y[0] + y[1] + y[2] + y[3];
  float ss = y[0]*y[0] + y[1]*y[1] + y[2]*y[2] + y[3]*y[3];
#pragma unroll
  for (int off = 1; off < 64; off <<= 1) {
    s  += __shfl_xor(s, off);
    ss += __shfl_xor(ss, off);
  }
  __shared__ float ws_s[4], ws_ss[4];
  const int wid = t >> 6;
  if ((t & 63) == 0) { ws_s[wid] = s; ws_ss[wid] = ss; }
  __syncthreads();
  s  = ws_s[0] + ws_s[1] + ws_s[2] + ws_s[3];
  ss = ws_ss[0] + ws_ss[1] + ws_ss[2] + ws_ss[3];
  const float mu   = s * (1.f / NV);
  const float var  = ss * (1.f / NV) - mu * mu;
  const float rstd = rsqrtf(var + LN_EPS);
  float4 gv = *(const float4*)(gamma + t * 4);
  float4 bv = *(const float4*)(beta + t * 4);
  float4 o;
  o.x = gv.x * (y[0] - mu) * rstd + bv.x;
  o.y = gv.y * (y[1] - mu) * rstd + bv.y;
  o.z = gv.z * (y[2] - mu) * rstd + bv.z;
  o.w = gv.w * (y[3] - mu) * rstd + bv.w;
  *(float4*)(out + (size_t)row * NV + t * 4) = o;
}

// ---------------------------------------------------------------------------
extern "C" void kernel_launch(void* const* d_in, const int* in_sizes, int n_in,
                              void* d_out, int out_size, void* d_ws, size_t ws_size,
                              hipStream_t stream) {
  const float* query = (const float*)d_in[0];
  const float* key_t = (const float*)d_in[1];
  const float* value = (const float*)d_in[2];
  const float* Wq    = (const float*)d_in[3];
  const float* Wk    = (const float*)d_in[4];
  const float* Wv    = (const float*)d_in[5];
  const float* gamma = (const float*)d_in[6];
  const float* beta  = (const float*)d_in[7];
  const int*   qmask = (const int*)d_in[8];
  const int*   vmask = (const int*)d_in[9];
  float* out = (float*)d_out;

  const size_t per = (size_t)NB * NH * SL * DH;  // 4,194,304 elements
  bf16_t* Qws = (bf16_t*)d_ws;
  bf16_t* Kws = Qws + per;
  bf16_t* Vws = Kws + per;
  bf16_t* Wtb = Vws + per;  // 3 * 1024*1024 bf16 = 6 MB

  wcvt<<<dim3(16, 16, 3), 256, 0, stream>>>(Wq, Wk, Wv, Wtb);
  proj_mfma<<<dim3(32, 8, 3), 256, 0, stream>>>(query, key_t, value, Wtb,
                                                Qws, Kws, Vws);
  attn_mfma<<<1024, 256, 0, stream>>>(Qws, Kws, Vws, qmask, vmask, out);
  ln_kernel<<<NB * SL, 256, 0, stream>>>(out, query, gamma, beta, out);
}

// Round 6
// 226.807 us; speedup vs baseline: 4.6913x; 1.0237x over previous
//
#include <hip/hip_runtime.h>
#include <math.h>

constexpr int NB = 2;      // batch
constexpr int SL = 2048;   // sequence length
constexpr int NV = 1024;   // model dim
constexpr int NH = 16;     // heads
constexpr int DH = 64;     // head dim
constexpr int NT = SL / 64;
constexpr float LN_EPS = 1e-3f;

typedef __bf16 bf16_t;
typedef __bf16 v8bf __attribute__((ext_vector_type(8)));
typedef float  v4f  __attribute__((ext_vector_type(4)));

__device__ __forceinline__ v8bf cvt8(float4 a, float4 b) {
  v8bf v;
  v[0] = (bf16_t)a.x; v[1] = (bf16_t)a.y; v[2] = (bf16_t)a.z; v[3] = (bf16_t)a.w;
  v[4] = (bf16_t)b.x; v[5] = (bf16_t)b.y; v[6] = (bf16_t)b.z; v[7] = (bf16_t)b.w;
  return v;
}
__device__ __forceinline__ unsigned pack_bf16(float a, float b) {
  unsigned short ua = __builtin_bit_cast(unsigned short, (bf16_t)a);
  unsigned short ub = __builtin_bit_cast(unsigned short, (bf16_t)b);
  return (unsigned)ua | ((unsigned)ub << 16);
}
// async global->LDS, 16B/lane; LDS dest = wave-uniform base + lane*16.
__device__ __forceinline__ void async_cp16(const void* g, void* l) {
  __builtin_amdgcn_global_load_lds(
      (const __attribute__((address_space(1))) unsigned int*)g,
      (__attribute__((address_space(3))) unsigned int*)l, 16, 0, 0);
}

// ---------------------------------------------------------------------------
// W transpose+convert: W[h][v][d] fp32 -> Wt[z][n=h*64+d][v] bf16.
// Scale (1/8 * log2e) folded into Wq (softmax then uses exp2 directly).
__global__ __launch_bounds__(256)
void wcvt(const float* __restrict__ Wq, const float* __restrict__ Wk,
          const float* __restrict__ Wv, bf16_t* __restrict__ Wt) {
  __shared__ float ls[64][65];
  const int z = blockIdx.z;
  const float* W = z == 0 ? Wq : (z == 1 ? Wk : Wv);
  const float sc = z == 0 ? 0.125f * 1.44269504f : 1.0f;
  const int h = blockIdx.y, v0 = blockIdx.x * 64;
  const int t = threadIdx.x;
  const int rr = t >> 4, c4 = t & 15;
  const float* src = W + ((size_t)h * NV + v0) * DH;
#pragma unroll
  for (int it = 0; it < 4; ++it) {
    float4 f = *(const float4*)(src + (size_t)(rr + it * 16) * DH + c4 * 4);
    ls[rr + it * 16][c4 * 4 + 0] = f.x;
    ls[rr + it * 16][c4 * 4 + 1] = f.y;
    ls[rr + it * 16][c4 * 4 + 2] = f.z;
    ls[rr + it * 16][c4 * 4 + 3] = f.w;
  }
  __syncthreads();
  const int dd = t >> 2, vq = t & 3;
  bf16_t tmp[16];
#pragma unroll
  for (int i = 0; i < 16; ++i) tmp[i] = (bf16_t)(ls[vq * 16 + i][dd] * sc);
  bf16_t* dst = Wt + ((size_t)z * NV + h * 64 + dd) * NV + v0 + vq * 16;
  *(v8bf*)dst = *(v8bf*)&tmp[0];
  *(v8bf*)(dst + 8) = *(v8bf*)&tmp[8];
}

// ---------------------------------------------------------------------------
// Projection GEMM: BK=32, double-buffered LDS, ONE barrier per iter (staging
// for k+1 issued right after the barrier -> a full compute iter of latency
// hiding). Q/K outputs [bh][l][d]; V output TRANSPOSED [bh][d][m] with the
// value mask folded in (vm in {0,1} => exact).
// Grid (32, 8, 3); 256 threads = 4 waves in 2x2, wave tile 64x64.
__global__ __launch_bounds__(256, 3)
void proj_mfma(const float* __restrict__ A0, const float* __restrict__ A1,
               const float* __restrict__ A2, const bf16_t* __restrict__ Wtb,
               const int* __restrict__ vmask,
               bf16_t* __restrict__ O0, bf16_t* __restrict__ O1,
               bf16_t* __restrict__ O2) {
  __shared__ __align__(16) float  As[2][128 * 32];   // 16KB x2, 128B rows
  __shared__ __align__(16) bf16_t Wsh[2][128 * 32];  // 8KB x2, 64B rows

  const int z = blockIdx.z;
  const float*  A   = z == 0 ? A0 : (z == 1 ? A1 : A2);
  bf16_t*       out = z == 0 ? O0 : (z == 1 ? O1 : O2);
  const bf16_t* W   = Wtb + (size_t)z * NV * NV;

  const int t = threadIdx.x, w = t >> 6, lane = t & 63;
  const int g = lane >> 4, lx = lane & 15;
  const int m0 = blockIdx.x * 128, n0 = blockIdx.y * 128;
  const int rbase = (w >> 1) * 64, cbase = (w & 1) * 64;

  auto stageA = [&](int k0, int buf) {
#pragma unroll
    for (int s = 0; s < 4; ++s) {
      const int r = w * 32 + s * 8 + (lane >> 3);
      const int c = (lane & 7) ^ (r & 7);
      async_cp16(A + (size_t)(m0 + r) * NV + k0 + c * 4,
                 (char*)As[buf] + (w * 32 + s * 8) * 128);
    }
  };
  auto stageW = [&](int k0, int buf) {
#pragma unroll
    for (int s = 0; s < 2; ++s) {
      const int r = w * 32 + s * 16 + (lane >> 2);
      const int c = (lane & 3) ^ (r & 3);
      async_cp16(W + (size_t)(n0 + r) * NV + k0 + c * 8,
                 (char*)Wsh[buf] + (w * 32 + s * 16) * 64);
    }
  };

  v4f acc[4][4] = {};
  stageA(0, 0);
  stageW(0, 0);

  for (int k0 = 0; k0 < NV; k0 += 32) {
    const int buf = (k0 >> 5) & 1;
    __syncthreads();  // drains this tile's async; orders prev reads vs restage
    if (k0 + 32 < NV) { stageA(k0 + 32, buf ^ 1); stageW(k0 + 32, buf ^ 1); }
    v8bf af[4], wf[4];
#pragma unroll
    for (int rt = 0; rt < 4; ++rt) {
      const int row = rbase + rt * 16 + lx;
      const int sw = row & 7;
      float4 f0 = *(const float4*)((const char*)As[buf] + row * 128 + ((2 * g)     ^ sw) * 16);
      float4 f1 = *(const float4*)((const char*)As[buf] + row * 128 + ((2 * g + 1) ^ sw) * 16);
      af[rt] = cvt8(f0, f1);
    }
#pragma unroll
    for (int ct = 0; ct < 4; ++ct) {
      const int row = cbase + ct * 16 + lx;
      wf[ct] = *(const v8bf*)((const char*)Wsh[buf] + row * 64 + (g ^ (row & 3)) * 16);
    }
#pragma unroll
    for (int rt = 0; rt < 4; ++rt)
#pragma unroll
      for (int ct = 0; ct < 4; ++ct)
        acc[rt][ct] = __builtin_amdgcn_mfma_f32_16x16x32_bf16(
            af[rt], wf[ct], acc[rt][ct], 0, 0, 0);
  }

  // epilogue. C-layout: row=(lane>>4)*4+reg, col=lane&15.
  if (z < 2) {  // Q/K: [bh][l][d]
#pragma unroll
    for (int rt = 0; rt < 4; ++rt) {
#pragma unroll
      for (int reg = 0; reg < 4; ++reg) {
        const int row = m0 + rbase + rt * 16 + g * 4 + reg;
        const int b = row >> 11, l = row & (SL - 1);
#pragma unroll
        for (int ct = 0; ct < 4; ++ct) {
          const int n = n0 + cbase + ct * 16 + lx;
          const int h = n >> 6, d = n & 63;
          out[((size_t)(b * NH + h) * SL + l) * DH + d] = (bf16_t)acc[rt][ct][reg];
        }
      }
    }
  } else {  // V: transposed [bh][d][m], vm folded in; b64 stores along m
#pragma unroll
    for (int rt = 0; rt < 4; ++rt) {
      const int row = m0 + rbase + rt * 16 + g * 4;  // regs = 4 consecutive m
      const int b = row >> 11, l = row & (SL - 1);
      float vm0 = (float)vmask[b * SL + l + 0];
      float vm1 = (float)vmask[b * SL + l + 1];
      float vm2 = (float)vmask[b * SL + l + 2];
      float vm3 = (float)vmask[b * SL + l + 3];
#pragma unroll
      for (int ct = 0; ct < 4; ++ct) {
        const int n = n0 + cbase + ct * 16 + lx;
        const int h = n >> 6, d = n & 63;
        uint2 u = {pack_bf16(acc[rt][ct][0] * vm0, acc[rt][ct][1] * vm1),
                   pack_bf16(acc[rt][ct][2] * vm2, acc[rt][ct][3] * vm3)};
        *(uint2*)&out[((size_t)(b * NH + h) * DH + d) * SL + l] = u;
      }
    }
  }
}

// ---------------------------------------------------------------------------
// Fused attention. Reference semantics: softmax denominator over ALL m
// (unmasked); PV numerator masked by tril (vm already folded into V^T); qm at
// epilogue. exp2, no max-tracking (log2e folded into Q via wcvt).
// Wave split: (mh, qh) halves of (m, q) -> K/V frag reads halved vs q-quarter
// split. K and V^T staged via global_load_lds, double-buffered, 1 barrier per
// tile. Cross-wave O / denominator reduced once at the end (Obuf aliases the
// staging buffers). XCD swizzle: all q-blocks of a bh on one XCD; heavy
// blocks (large qb) scheduled first.
// Block: 64 q-rows. Grid 1024 (1D).
__global__ __launch_bounds__(256, 3)
void attn_mfma(const bf16_t* __restrict__ Qg, const bf16_t* __restrict__ Kg,
               const bf16_t* __restrict__ Vtg_all, const int* __restrict__ qmask,
               float* __restrict__ Xout) {
  struct LoopBufs { bf16_t kbuf[2][64 * 64]; bf16_t vbuf[2][64 * 64]; };
  union __align__(16) SU { LoopBufs lp; float Obuf[2][64][36]; };
  __shared__ SU su;
  __shared__ bf16_t Ps[64][72];   // P^T strip [q][m], quadrant-disjoint per wave
  __shared__ float sums[2][64];   // [mh][q] denominator partials

  const int id = blockIdx.x;
  const int bh = (id & 7) | ((id >> 8) << 3);  // same-XCD for fixed bh
  const int qb = 31 - ((id >> 3) & 31);        // heavy blocks first
  const int t = threadIdx.x, w = t >> 6, lane = t & 63;
  const int g = lane >> 4, lx = lane & 15;
  const int mh = w >> 1, qh = w & 1;
  const int b = bh >> 4, h = bh & 15;
  const int l0 = qb * 64;

  const bf16_t* Kb  = Kg + (size_t)bh * SL * DH;
  const bf16_t* Vtg = Vtg_all + (size_t)bh * DH * SL;  // [d][m]

  // persistent Q B-frags: wave covers q in [l0+qh*32, +32)
  v8bf qf[2][2];
#pragma unroll
  for (int qt = 0; qt < 2; ++qt)
#pragma unroll
    for (int ks = 0; ks < 2; ++ks)
      qf[qt][ks] = *(const v8bf*)&Qg[((size_t)bh * SL + l0 + qh * 32 + qt * 16 + lx) * DH +
                                     ks * 32 + g * 8];

  v4f O[2][4] = {};          // [qt][dt]
  float suml[2] = {0.f, 0.f};

  auto stageK = [&](int mb, int buf) {
#pragma unroll
    for (int s = 0; s < 2; ++s) {
      const int r = w * 16 + s * 8 + (lane >> 3);
      const int c = (lane & 7) ^ (r & 7);
      async_cp16(Kb + (size_t)(mb + r) * DH + c * 8,
                 (char*)su.lp.kbuf[buf] + (w * 16 + s * 8) * 128);
    }
  };
  auto stageV = [&](int mb, int buf) {
#pragma unroll
    for (int s = 0; s < 2; ++s) {
      const int r = w * 16 + s * 8 + (lane >> 3);  // r = d row
      const int c = (lane & 7) ^ (r & 7);
      async_cp16(Vtg + (size_t)r * SL + mb + c * 8,
                 (char*)su.lp.vbuf[buf] + (w * 16 + s * 8) * 128);
    }
  };

  stageK(0, 0);
  stageV(0, 0);

  // ---- active tiles (mt <= qb): S, P, PV ----
  for (int mt = 0; mt <= qb; ++mt) {
    const int m0 = mt * 64, pb = mt & 1;
    __syncthreads();  // staged buffers for tile mt drained; prev reads done
    if (mt + 1 < NT)  stageK(m0 + 64, pb ^ 1);
    if (mt + 1 <= qb) stageV(m0 + 64, pb ^ 1);

    // S^T strips: wave (mh,qh): rows m in mh-half, cols q in qh-half
    v4f S[2][2] = {};
#pragma unroll
    for (int ks = 0; ks < 2; ++ks)
#pragma unroll
      for (int mt2 = 0; mt2 < 2; ++mt2) {
        const int row = mh * 32 + mt2 * 16 + lx;
        const int slot = (ks * 4 + g) ^ (row & 7);
        v8bf kf = *(const v8bf*)((const char*)su.lp.kbuf[pb] + row * 128 + slot * 16);
#pragma unroll
        for (int qt = 0; qt < 2; ++qt)
          S[mt2][qt] = __builtin_amdgcn_mfma_f32_16x16x32_bf16(
              kf, qf[qt][ks], S[mt2][qt], 0, 0, 0);
      }

    const bool diag = (mt == qb);
#pragma unroll
    for (int mt2 = 0; mt2 < 2; ++mt2)
#pragma unroll
      for (int qt = 0; qt < 2; ++qt) {
        float e0 = __builtin_amdgcn_exp2f(S[mt2][qt][0]);
        float e1 = __builtin_amdgcn_exp2f(S[mt2][qt][1]);
        float e2 = __builtin_amdgcn_exp2f(S[mt2][qt][2]);
        float e3 = __builtin_amdgcn_exp2f(S[mt2][qt][3]);
        suml[qt] += (e0 + e1) + (e2 + e3);
        if (diag) {
          const int ml = mh * 32 + mt2 * 16 + g * 4;
          const int ql = qh * 32 + qt * 16 + lx;
          e0 = (ml + 0 <= ql) ? e0 : 0.f;
          e1 = (ml + 1 <= ql) ? e1 : 0.f;
          e2 = (ml + 2 <= ql) ? e2 : 0.f;
          e3 = (ml + 3 <= ql) ? e3 : 0.f;
        }
        uint2 u = {pack_bf16(e0, e1), pack_bf16(e2, e3)};
        *(uint2*)&Ps[qh * 32 + qt * 16 + lx][mh * 32 + mt2 * 16 + g * 4] = u;
      }

    // O += P[.,mh-half] . V[mh-half,.]  (Ps quadrant written & read by this wave)
    v8bf pf[2];
#pragma unroll
    for (int qt = 0; qt < 2; ++qt)
      pf[qt] = *(const v8bf*)&Ps[qh * 32 + qt * 16 + lx][mh * 32 + g * 8];
#pragma unroll
    for (int dt = 0; dt < 4; ++dt) {
      const int row = dt * 16 + lx;
      const int slot = (mh * 4 + g) ^ (row & 7);
      v8bf vf = *(const v8bf*)((const char*)su.lp.vbuf[pb] + row * 128 + slot * 16);
#pragma unroll
      for (int qt = 0; qt < 2; ++qt)
        O[qt][dt] = __builtin_amdgcn_mfma_f32_16x16x32_bf16(
            pf[qt], vf, O[qt][dt], 0, 0, 0);
    }
  }

  // ---- future tiles (mt > qb): denominator only ----
  for (int mt = qb + 1; mt < NT; ++mt) {
    const int pb = mt & 1;
    __syncthreads();
    if (mt + 1 < NT) stageK(mt * 64 + 64, pb ^ 1);
    v4f S[2][2] = {};
#pragma unroll
    for (int ks = 0; ks < 2; ++ks)
#pragma unroll
      for (int mt2 = 0; mt2 < 2; ++mt2) {
        const int row = mh * 32 + mt2 * 16 + lx;
        const int slot = (ks * 4 + g) ^ (row & 7);
        v8bf kf = *(const v8bf*)((const char*)su.lp.kbuf[pb] + row * 128 + slot * 16);
#pragma unroll
        for (int qt = 0; qt < 2; ++qt)
          S[mt2][qt] = __builtin_amdgcn_mfma_f32_16x16x32_bf16(
              kf, qf[qt][ks], S[mt2][qt], 0, 0, 0);
      }
#pragma unroll
    for (int mt2 = 0; mt2 < 2; ++mt2)
#pragma unroll
      for (int qt = 0; qt < 2; ++qt)
        suml[qt] += (__builtin_amdgcn_exp2f(S[mt2][qt][0]) +
                     __builtin_amdgcn_exp2f(S[mt2][qt][1])) +
                    (__builtin_amdgcn_exp2f(S[mt2][qt][2]) +
                     __builtin_amdgcn_exp2f(S[mt2][qt][3]));
  }

  // ---- cross-wave reduction (denominator + O across mh) ----
  suml[0] += __shfl_xor(suml[0], 16); suml[0] += __shfl_xor(suml[0], 32);
  suml[1] += __shfl_xor(suml[1], 16); suml[1] += __shfl_xor(suml[1], 32);
  __syncthreads();  // all loop reads done; safe to alias Obuf & write sums
  if (g == 0) {
    sums[mh][qh * 32 + lx]      = suml[0];
    sums[mh][qh * 32 + 16 + lx] = suml[1];
  }
  if (mh == 0) {
#pragma unroll
    for (int qt = 0; qt < 2; ++qt)
#pragma unroll
      for (int dt = 0; dt < 4; ++dt)
        *(v4f*)&su.Obuf[qh][dt * 16 + lx][qt * 16 + g * 4] = O[qt][dt];
  }
  __syncthreads();
  if (mh == 1) {
#pragma unroll
    for (int qt = 0; qt < 2; ++qt) {
#pragma unroll
      for (int dt = 0; dt < 4; ++dt)
        O[qt][dt] += *(const v4f*)&su.Obuf[qh][dt * 16 + lx][qt * 16 + g * 4];
#pragma unroll
      for (int reg = 0; reg < 4; ++reg) {
        const int ql = qh * 32 + qt * 16 + g * 4 + reg;
        const int q = l0 + ql;
        const float den = sums[0][ql] + sums[1][ql];
        const float inv = (float)qmask[b * SL + q] / den;
#pragma unroll
        for (int dt = 0; dt < 4; ++dt)
          Xout[((size_t)(b * SL + q)) * NV + h * DH + dt * 16 + lx] =
              O[qt][dt][reg] * inv;
      }
    }
  }
}

// ---------------------------------------------------------------------------
// Residual + LayerNorm over last dim (V=1024). 2 rows per block for ILP.
__global__ __launch_bounds__(256)
void ln_kernel(const float* __restrict__ X, const float* __restrict__ query,
               const float* __restrict__ gamma, const float* __restrict__ beta,
               float* __restrict__ out) {
  const int row0 = blockIdx.x * 2;
  const int t = threadIdx.x;
  float4 gv = *(const float4*)(gamma + t * 4);
  float4 bv = *(const float4*)(beta + t * 4);
  float y[2][4];
  float s[2], ss[2];
#pragma unroll
  for (int r = 0; r < 2; ++r) {
    float4 xv = *(const float4*)(X + (size_t)(row0 + r) * NV + t * 4);
    float4 qv = *(const float4*)(query + (size_t)(row0 + r) * NV + t * 4);
    y[r][0] = xv.x + qv.x; y[r][1] = xv.y + qv.y;
    y[r][2] = xv.z + qv.z; y[r][3] = xv.w + qv.w;
    s[r]  = (y[r][0] + y[r][1]) + (y[r][2] + y[r][3]);
    ss[r] = (y[r][0]*y[r][0] + y[r][1]*y[r][1]) + (y[r][2]*y[r][2] + y[r][3]*y[r][3]);
  }
#pragma unroll
  for (int off = 1; off < 64; off <<= 1) {
    s[0]  += __shfl_xor(s[0], off);  ss[0] += __shfl_xor(ss[0], off);
    s[1]  += __shfl_xor(s[1], off);  ss[1] += __shfl_xor(ss[1], off);
  }
  __shared__ float wsum[2][2][4];  // [r][{s,ss}][wave]
  const int wid = t >> 6;
  if ((t & 63) == 0) {
    wsum[0][0][wid] = s[0]; wsum[0][1][wid] = ss[0];
    wsum[1][0][wid] = s[1]; wsum[1][1][wid] = ss[1];
  }
  __syncthreads();
#pragma unroll
  for (int r = 0; r < 2; ++r) {
    float sr  = (wsum[r][0][0] + wsum[r][0][1]) + (wsum[r][0][2] + wsum[r][0][3]);
    float ssr = (wsum[r][1][0] + wsum[r][1][1]) + (wsum[r][1][2] + wsum[r][1][3]);
    const float mu   = sr * (1.f / NV);
    const float var  = ssr * (1.f / NV) - mu * mu;
    const float rstd = rsqrtf(var + LN_EPS);
    float4 o;
    o.x = gv.x * (y[r][0] - mu) * rstd + bv.x;
    o.y = gv.y * (y[r][1] - mu) * rstd + bv.y;
    o.z = gv.z * (y[r][2] - mu) * rstd + bv.z;
    o.w = gv.w * (y[r][3] - mu) * rstd + bv.w;
    *(float4*)(out + (size_t)(row0 + r) * NV + t * 4) = o;
  }
}

// ---------------------------------------------------------------------------
extern "C" void kernel_launch(void* const* d_in, const int* in_sizes, int n_in,
                              void* d_out, int out_size, void* d_ws, size_t ws_size,
                              hipStream_t stream) {
  const float* query = (const float*)d_in[0];
  const float* key_t = (const float*)d_in[1];
  const float* value = (const float*)d_in[2];
  const float* Wq    = (const float*)d_in[3];
  const float* Wk    = (const float*)d_in[4];
  const float* Wv    = (const float*)d_in[5];
  const float* gamma = (const float*)d_in[6];
  const float* beta  = (const float*)d_in[7];
  const int*   qmask = (const int*)d_in[8];
  const int*   vmask = (const int*)d_in[9];
  float* out = (float*)d_out;

  const size_t per = (size_t)NB * NH * SL * DH;  // 4,194,304 elements
  bf16_t* Qws = (bf16_t*)d_ws;
  bf16_t* Kws = Qws + per;
  bf16_t* Vws = Kws + per;   // transposed [bh][d][m], vm-masked
  bf16_t* Wtb = Vws + per;   // 3 * 1024*1024 bf16 = 6 MB

  wcvt<<<dim3(16, 16, 3), 256, 0, stream>>>(Wq, Wk, Wv, Wtb);
  proj_mfma<<<dim3(32, 8, 3), 256, 0, stream>>>(query, key_t, value, Wtb,
                                                vmask, Qws, Kws, Vws);
  attn_mfma<<<1024, 256, 0, stream>>>(Qws, Kws, Vws, qmask, out);
  ln_kernel<<<NB * SL / 2, 256, 0, stream>>>(out, query, gamma, beta, out);
}